// Round 14
// baseline (274.700 us; speedup 1.0000x reference)
//
#include <hip/hip_runtime.h>
#include <math.h>

#define N_NODES 20000
#define KNBR 32
#define DIM 128
#define EDIM 64
#define HEADS 8
#define OUTD 128
#define FFD 512
#define LN_EPS 1e-5f

typedef __attribute__((ext_vector_type(8))) short short8v;
typedef __attribute__((ext_vector_type(4))) float f32x4;

__device__ __forceinline__ unsigned short f2bf(float f) {
    unsigned u = __builtin_bit_cast(unsigned, f);
    u += 0x7fffu + ((u >> 16) & 1u);
    return (unsigned short)(u >> 16);
}
__device__ __forceinline__ float bfhi2f(unsigned u_hi16) {
    return __builtin_bit_cast(float, u_hi16);
}

// pack 8 f32 -> 8 bf16 via the proven scalar path
__device__ __forceinline__ short8v pack8(const float4 a, const float4 b) {
    short8v r;
    r[0] = (short)f2bf(a.x); r[1] = (short)f2bf(a.y);
    r[2] = (short)f2bf(a.z); r[3] = (short)f2bf(a.w);
    r[4] = (short)f2bf(b.x); r[5] = (short)f2bf(b.y);
    r[6] = (short)f2bf(b.z); r[7] = (short)f2bf(b.w);
    return r;
}

// DPP 16-lane all-lanes sum (VALU only, no DS)
template <int CTRL>
__device__ __forceinline__ float dpp_addf(float x) {
    const int s = __builtin_bit_cast(int, x);
    const int p = __builtin_amdgcn_update_dpp(s, s, CTRL, 0xF, 0xF, true);
    return x + __builtin_bit_cast(float, p);
}
__device__ __forceinline__ float red16(float x) {
    x = dpp_addf<0xB1>(x);
    x = dpp_addf<0x4E>(x);
    x = dpp_addf<0x141>(x);
    x = dpp_addf<0x140>(x);
    return x;
}

// ---------------------------------------------------------------------------
// K0: weight prep (round-7 proven version).
// ---------------------------------------------------------------------------
__global__ __launch_bounds__(256) void k0_prep(
    const float* __restrict__ Wk, const float* __restrict__ Wv,
    const float* __restrict__ Wo, const float* __restrict__ W1,
    const float* __restrict__ W2,
    unsigned short* __restrict__ WkvTf, unsigned short* __restrict__ WoT,
    unsigned short* __restrict__ W1T, unsigned short* __restrict__ W2T)
{
    const int idx = blockIdx.x * 256 + threadIdx.x;   // 163840 total
    if (idx < 16384) {
        const int frag = idx >> 9;          // cc*2 + s
        const int e    = idx & 511;
        const int lane = e >> 3, j = e & 7;
        const int cc = frag >> 1, s = frag & 1;
        const int c  = cc * 16 + (lane & 15);
        const int m  = s * 32 + (lane >> 4) * 8 + j;
        WkvTf[idx] = f2bf((c < 128) ? Wk[(size_t)(128 + m) * 128 + c]
                                    : Wv[(size_t)(128 + m) * 128 + (c - 128)]);
    } else if (idx < 32768) {
        const int j = idx - 16384, c = j >> 7, d = j & 127;
        WoT[j] = f2bf(Wo[(size_t)d * 128 + c]);
    } else if (idx < 98304) {
        const int j = idx - 32768, f = j >> 7, d = j & 127;
        W1T[j] = f2bf(W1[(size_t)d * 512 + f]);
    } else {
        const int j = idx - 98304, c = j >> 9, f = j & 511;
        W2T[j] = f2bf(W2[(size_t)f * 128 + c]);
    }
}

// ---------------------------------------------------------------------------
// K1 (round-7 proven scalar version)
// ---------------------------------------------------------------------------
__global__ __launch_bounds__(256) void k1_ln_q_p(
    const float* __restrict__ node_rep, const float* __restrict__ mask,
    const float* __restrict__ ln1_s, const float* __restrict__ ln1_b,
    const float* __restrict__ Wq, const float* __restrict__ bq,
    const float* __restrict__ Wk, const float* __restrict__ bk,
    const float* __restrict__ Wv, const float* __restrict__ bv,
    float* __restrict__ xout, float* __restrict__ qout,
    unsigned short* __restrict__ Pp)
{
    __shared__ float xs[8][DIM];
    const int t = threadIdx.x;
    const int nb = blockIdx.x * 8;
    const int g = t >> 5;
    const int lane = t & 31;
    const int node = nb + g;

    float4 v = reinterpret_cast<const float4*>(node_rep + (size_t)node * DIM)[lane];
    float s1 = v.x + v.y + v.z + v.w;
    float s2 = v.x * v.x + v.y * v.y + v.z * v.z + v.w * v.w;
    #pragma unroll
    for (int off = 16; off; off >>= 1) {
        s1 += __shfl_xor(s1, off, 32);
        s2 += __shfl_xor(s2, off, 32);
    }
    const float mean = s1 * (1.0f / DIM);
    const float var  = s2 * (1.0f / DIM) - mean * mean;
    const float rs   = rsqrtf(var + LN_EPS);
    const float mk   = mask[node];

    float4 sc = reinterpret_cast<const float4*>(ln1_s)[lane];
    float4 of = reinterpret_cast<const float4*>(ln1_b)[lane];
    float4 xo;
    xo.x = ((v.x - mean) * rs * sc.x + of.x) * mk;
    xo.y = ((v.y - mean) * rs * sc.y + of.y) * mk;
    xo.z = ((v.z - mean) * rs * sc.z + of.z) * mk;
    xo.w = ((v.w - mean) * rs * sc.w + of.w) * mk;
    reinterpret_cast<float4*>(xout + (size_t)node * DIM)[lane] = xo;
    const int c0 = lane * 4;
    xs[g][c0 + 0] = xo.x; xs[g][c0 + 1] = xo.y;
    xs[g][c0 + 2] = xo.z; xs[g][c0 + 3] = xo.w;
    __syncthreads();

    const int col = t & 127;
    const int n0  = t >> 7;
    const int c = t;
    const float* wq = Wq + col;
    const float* wp = (c < 128) ? (Wk + c) : (Wv + (c - 128));

    float accq[4] = {0.f, 0.f, 0.f, 0.f};
    float accp[8] = {0.f, 0.f, 0.f, 0.f, 0.f, 0.f, 0.f, 0.f};
    for (int d = 0; d < DIM; ++d) {
        const float wqd = wq[(size_t)d * 128];
        const float wpd = wp[(size_t)d * 128];
        #pragma unroll
        for (int i = 0; i < 4; ++i) accq[i] += xs[n0 + 2 * i][d] * wqd;
        #pragma unroll
        for (int i = 0; i < 8; ++i) accp[i] += xs[i][d] * wpd;
    }
    const float bqv = bq[col];
    #pragma unroll
    for (int i = 0; i < 4; ++i)
        qout[(size_t)(nb + n0 + 2 * i) * DIM + col] = accq[i] + bqv;

    const float bpv = (c < 128) ? bk[c] : bv[c - 128];
    #pragma unroll
    for (int i = 0; i < 8; ++i)
        Pp[(size_t)(nb + i) * 256 + c] = f2bf(accp[i] + bpv);
}

// ---------------------------------------------------------------------------
// K2: phase-split attention, TRUE STATE REDUCED to cross the 128-reg cliff:
//   - attn weights round-trip through LDS (2 KB, same-wave RAW, no barrier)
//   - edge A-fragments reloaded in phase B (L2-resident between phases)
//   peak live state ~112 regs incl. 64 acc -> (256,4) bound = 4 waves/SIMD
//   with no spills (round 12's failure had ~176 true state).
// ---------------------------------------------------------------------------
__global__ __launch_bounds__(256, 4) void k2_attn(
    const float* __restrict__ qg, const float* __restrict__ edge_feat,
    const unsigned short* __restrict__ Pp,
    const unsigned short* __restrict__ WkvTf,
    const int* __restrict__ senders,
    float* __restrict__ og)
{
    __shared__ unsigned attls[4][8][4][4];   // [wave][head][lg][j], 2 KB

    const int t = threadIdx.x;
    const int w = t >> 6, l = t & 63;
    const int n = blockIdx.x * 4 + w;
    const int l15 = l & 15, lg = l >> 4;

    const int s0 = senders[n * KNBR + l15];
    const int s1 = senders[n * KNBR + 16 + l15];

    // identity B-fragments (8 regs, live across both phases)
    short8v ib1, ib2;
    #pragma unroll
    for (int j = 0; j < 8; ++j) {
        const int m = lg * 8 + j;
        ib1[j] = (m == l15)      ? (short)0x3F80 : (short)0;
        ib2[j] = (m == l15 + 16) ? (short)0x3F80 : (short)0;
    }

    // ---- phase A: kk (cols 0..127) ----
    short8v afr[2][2];
    #pragma unroll
    for (int r = 0; r < 2; ++r) {
        #pragma unroll
        for (int s = 0; s < 2; ++s) {
            const float* ep = edge_feat
                + ((size_t)n * KNBR + 16 * r + l15) * EDIM + s * 32 + lg * 8;
            const float4 e0 = *reinterpret_cast<const float4*>(ep);
            const float4 e1 = *reinterpret_cast<const float4*>(ep + 4);
            afr[r][s] = pack8(e0, e1);
        }
    }

    f32x4 acc[2][8];
    #pragma unroll
    for (int r = 0; r < 2; ++r)
        #pragma unroll
        for (int cc = 0; cc < 8; ++cc)
            acc[r][cc] = (f32x4){0.f, 0.f, 0.f, 0.f};

    #pragma unroll
    for (int cc = 0; cc < 8; ++cc) {
        #pragma unroll
        for (int s = 0; s < 2; ++s) {
            const short8v b = *reinterpret_cast<const short8v*>(
                WkvTf + (((size_t)(cc * 2 + s)) << 9) + l * 8);
            acc[0][cc] = __builtin_amdgcn_mfma_f32_16x16x32_bf16(
                afr[0][s], b, acc[0][cc], 0, 0, 0);
            acc[1][cc] = __builtin_amdgcn_mfma_f32_16x16x32_bf16(
                afr[1][s], b, acc[1][cc], 0, 0, 0);
        }
    }
    #pragma unroll
    for (int c2 = 0; c2 < 4; ++c2) {
        const short8v pa0 = *reinterpret_cast<const short8v*>(
            Pp + (size_t)s0 * 256 + c2 * 32 + lg * 8);
        const short8v pa1 = *reinterpret_cast<const short8v*>(
            Pp + (size_t)s1 * 256 + c2 * 32 + lg * 8);
        acc[0][2 * c2]     = __builtin_amdgcn_mfma_f32_16x16x32_bf16(
            pa0, ib1, acc[0][2 * c2], 0, 0, 0);
        acc[0][2 * c2 + 1] = __builtin_amdgcn_mfma_f32_16x16x32_bf16(
            pa0, ib2, acc[0][2 * c2 + 1], 0, 0, 0);
        acc[1][2 * c2]     = __builtin_amdgcn_mfma_f32_16x16x32_bf16(
            pa1, ib1, acc[1][2 * c2], 0, 0, 0);
        acc[1][2 * c2 + 1] = __builtin_amdgcn_mfma_f32_16x16x32_bf16(
            pa1, ib2, acc[1][2 * c2 + 1], 0, 0, 0);
    }

    // logits -> softmax -> attn weights (x 1/s) -> bf16 packed -> LDS
    #pragma unroll
    for (int h = 0; h < 8; ++h) {
        const float qv = qg[(size_t)n * DIM + h * 16 + l15];
        float tm[8];
        #pragma unroll
        for (int r = 0; r < 2; ++r)
            #pragma unroll
            for (int i = 0; i < 4; ++i)
                tm[r * 4 + i] = acc[r][h][i] * qv;
        #pragma unroll
        for (int k = 0; k < 8; ++k) tm[k] = red16(tm[k]);
        float m = tm[0];
        #pragma unroll
        for (int k = 1; k < 8; ++k) m = fmaxf(m, tm[k]);
        m = fmaxf(m, __shfl_xor(m, 16, 64));
        m = fmaxf(m, __shfl_xor(m, 32, 64));
        float s = 0.f;
        #pragma unroll
        for (int k = 0; k < 8; ++k) {
            tm[k] = __expf((tm[k] - m) * 0.25f);
            s += tm[k];
        }
        s += __shfl_xor(s, 16, 64);
        s += __shfl_xor(s, 32, 64);
        const float inv = 1.0f / s;
        uint4 ap;
        ap.x = (unsigned)f2bf(tm[0] * inv) | ((unsigned)f2bf(tm[1] * inv) << 16);
        ap.y = (unsigned)f2bf(tm[2] * inv) | ((unsigned)f2bf(tm[3] * inv) << 16);
        ap.z = (unsigned)f2bf(tm[4] * inv) | ((unsigned)f2bf(tm[5] * inv) << 16);
        ap.w = (unsigned)f2bf(tm[6] * inv) | ((unsigned)f2bf(tm[7] * inv) << 16);
        if (l15 == 0)
            *reinterpret_cast<uint4*>(&attls[w][h][lg][0]) = ap;
    }

    // ---- phase B: vv (cols 128..255), acc + afr registers reused ----
    #pragma unroll
    for (int r = 0; r < 2; ++r) {
        #pragma unroll
        for (int s = 0; s < 2; ++s) {
            const float* ep = edge_feat
                + ((size_t)n * KNBR + 16 * r + l15) * EDIM + s * 32 + lg * 8;
            const float4 e0 = *reinterpret_cast<const float4*>(ep);
            const float4 e1 = *reinterpret_cast<const float4*>(ep + 4);
            afr[r][s] = pack8(e0, e1);
        }
    }

    #pragma unroll
    for (int r = 0; r < 2; ++r)
        #pragma unroll
        for (int cc = 0; cc < 8; ++cc)
            acc[r][cc] = (f32x4){0.f, 0.f, 0.f, 0.f};

    #pragma unroll
    for (int cc = 0; cc < 8; ++cc) {
        #pragma unroll
        for (int s = 0; s < 2; ++s) {
            const short8v b = *reinterpret_cast<const short8v*>(
                WkvTf + (((size_t)((8 + cc) * 2 + s)) << 9) + l * 8);
            acc[0][cc] = __builtin_amdgcn_mfma_f32_16x16x32_bf16(
                afr[0][s], b, acc[0][cc], 0, 0, 0);
            acc[1][cc] = __builtin_amdgcn_mfma_f32_16x16x32_bf16(
                afr[1][s], b, acc[1][cc], 0, 0, 0);
        }
    }
    #pragma unroll
    for (int c2 = 0; c2 < 4; ++c2) {
        const short8v pa0 = *reinterpret_cast<const short8v*>(
            Pp + (size_t)s0 * 256 + 128 + c2 * 32 + lg * 8);
        const short8v pa1 = *reinterpret_cast<const short8v*>(
            Pp + (size_t)s1 * 256 + 128 + c2 * 32 + lg * 8);
        acc[0][2 * c2]     = __builtin_amdgcn_mfma_f32_16x16x32_bf16(
            pa0, ib1, acc[0][2 * c2], 0, 0, 0);
        acc[0][2 * c2 + 1] = __builtin_amdgcn_mfma_f32_16x16x32_bf16(
            pa0, ib2, acc[0][2 * c2 + 1], 0, 0, 0);
        acc[1][2 * c2]     = __builtin_amdgcn_mfma_f32_16x16x32_bf16(
            pa1, ib1, acc[1][2 * c2], 0, 0, 0);
        acc[1][2 * c2 + 1] = __builtin_amdgcn_mfma_f32_16x16x32_bf16(
            pa1, ib2, acc[1][2 * c2 + 1], 0, 0, 0);
    }

    // PV per head: attn weights (incl. 1/s) read back from LDS (broadcast)
    #pragma unroll
    for (int h = 0; h < 8; ++h) {
        const uint4 ap = *reinterpret_cast<const uint4*>(&attls[w][h][lg][0]);
        float ov = 0.f;
        ov += bfhi2f(ap.x << 16)         * acc[0][h][0];
        ov += bfhi2f(ap.x & 0xffff0000u) * acc[0][h][1];
        ov += bfhi2f(ap.y << 16)         * acc[0][h][2];
        ov += bfhi2f(ap.y & 0xffff0000u) * acc[0][h][3];
        ov += bfhi2f(ap.z << 16)         * acc[1][h][0];
        ov += bfhi2f(ap.z & 0xffff0000u) * acc[1][h][1];
        ov += bfhi2f(ap.w << 16)         * acc[1][h][2];
        ov += bfhi2f(ap.w & 0xffff0000u) * acc[1][h][3];
        ov += __shfl_xor(ov, 16, 64);
        ov += __shfl_xor(ov, 32, 64);
        if (lg == 0)
            og[(size_t)n * DIM + h * 16 + l15] = ov;
    }
}

// ---------------------------------------------------------------------------
// K3 (MFMA, proven)
// ---------------------------------------------------------------------------
__device__ __forceinline__ void lds_wr16(unsigned short* base, int row, int col,
                                         unsigned short v) {
    const int byte = row * 256 + (((col * 2) ^ ((row & 7) << 4)));
    *reinterpret_cast<unsigned short*>(reinterpret_cast<char*>(base) + byte) = v;
}
__device__ __forceinline__ short8v lds_rd128(const unsigned short* base, int row,
                                             int colbyte) {
    const int byte = row * 256 + ((colbyte) ^ ((row & 7) << 4));
    return *reinterpret_cast<const short8v*>(
        reinterpret_cast<const char*>(base) + byte);
}

__global__ __launch_bounds__(256) void k3_ffn(
    const float* __restrict__ og, const float* __restrict__ xg,
    const float* __restrict__ mask,
    const unsigned short* __restrict__ WoT, const float* __restrict__ bo,
    const float* __restrict__ ln2_s, const float* __restrict__ ln2_b,
    const unsigned short* __restrict__ W1T, const float* __restrict__ b1,
    const unsigned short* __restrict__ W2T, const float* __restrict__ b2,
    float* __restrict__ outp)
{
    __shared__ unsigned short hls[64 * 128];
    __shared__ unsigned short tls[64 * 128];

    const int t = threadIdx.x;
    const int w = t >> 6, l = t & 63;
    const int l15 = l & 15, lg = l >> 4;
    const int nb = blockIdx.x * 64;
    const int arow = w * 16 + l15;
    const int anode = nb + arow;
    const int r0 = lg * 4;

    float mk[4];
    #pragma unroll
    for (int i = 0; i < 4; ++i) {
        const int node = nb + w * 16 + r0 + i;
        mk[i] = (node < N_NODES) ? mask[node] : 0.f;
    }

    f32x4 acc1[8];
    #pragma unroll
    for (int ct = 0; ct < 8; ++ct) acc1[ct] = (f32x4){0.f, 0.f, 0.f, 0.f};
    #pragma unroll
    for (int kc = 0; kc < 4; ++kc) {
        short8v afr = {0, 0, 0, 0, 0, 0, 0, 0};
        if (anode < N_NODES) {
            const float* op = og + (size_t)anode * DIM + kc * 32 + lg * 8;
            const float4 e0 = *reinterpret_cast<const float4*>(op);
            const float4 e1 = *reinterpret_cast<const float4*>(op + 4);
            afr = pack8(e0, e1);
        }
        #pragma unroll
        for (int ct = 0; ct < 8; ++ct) {
            const short8v b = *reinterpret_cast<const short8v*>(
                WoT + (size_t)(ct * 16 + l15) * DIM + kc * 32 + lg * 8);
            acc1[ct] = __builtin_amdgcn_mfma_f32_16x16x32_bf16(afr, b, acc1[ct], 0, 0, 0);
        }
    }

    float s1[4] = {0.f, 0.f, 0.f, 0.f}, s2[4] = {0.f, 0.f, 0.f, 0.f};
    #pragma unroll
    for (int ct = 0; ct < 8; ++ct) {
        const float bov = bo[ct * 16 + l15];
        #pragma unroll
        for (int i = 0; i < 4; ++i) {
            const float v2 = (acc1[ct][i] + bov) * mk[i];
            acc1[ct][i] = v2;
            s1[i] += v2; s2[i] += v2 * v2;
        }
    }
    #pragma unroll
    for (int off = 1; off <= 8; off <<= 1) {
        #pragma unroll
        for (int i = 0; i < 4; ++i) {
            s1[i] += __shfl_xor(s1[i], off, 64);
            s2[i] += __shfl_xor(s2[i], off, 64);
        }
    }
    float mean[4], rsv[4];
    #pragma unroll
    for (int i = 0; i < 4; ++i) {
        mean[i] = s1[i] * (1.0f / OUTD);
        const float var = s2[i] * (1.0f / OUTD) - mean[i] * mean[i];
        rsv[i] = rsqrtf(var + LN_EPS);
    }
    #pragma unroll
    for (int ct = 0; ct < 8; ++ct) {
        const int col = ct * 16 + l15;
        const float sc = ln2_s[col], ofs = ln2_b[col];
        #pragma unroll
        for (int i = 0; i < 4; ++i) {
            const float h = (acc1[ct][i] - mean[i]) * rsv[i] * sc + ofs;
            lds_wr16(hls, w * 16 + r0 + i, col, f2bf(h));
        }
    }
    __syncthreads();

    short8v hfr[4];
    #pragma unroll
    for (int kc = 0; kc < 4; ++kc)
        hfr[kc] = lds_rd128(hls, arow, kc * 64 + lg * 16);

    f32x4 acc3[8];
    #pragma unroll
    for (int ct = 0; ct < 8; ++ct) acc3[ct] = (f32x4){0.f, 0.f, 0.f, 0.f};

    for (int chunk = 0; chunk < 4; ++chunk) {
        f32x4 acc2[8];
        #pragma unroll
        for (int ct = 0; ct < 8; ++ct) acc2[ct] = (f32x4){0.f, 0.f, 0.f, 0.f};
        #pragma unroll
        for (int kc = 0; kc < 4; ++kc) {
            #pragma unroll
            for (int ct = 0; ct < 8; ++ct) {
                const short8v b = *reinterpret_cast<const short8v*>(
                    W1T + (size_t)(chunk * 128 + ct * 16 + l15) * DIM + kc * 32 + lg * 8);
                acc2[ct] = __builtin_amdgcn_mfma_f32_16x16x32_bf16(hfr[kc], b, acc2[ct], 0, 0, 0);
            }
        }
        #pragma unroll
        for (int ct = 0; ct < 8; ++ct) {
            const float bv = b1[chunk * 128 + ct * 16 + l15];
            #pragma unroll
            for (int i = 0; i < 4; ++i) {
                const float tv = fmaxf(acc2[ct][i] + bv, 0.f);
                lds_wr16(tls, w * 16 + r0 + i, ct * 16 + l15, f2bf(tv));
            }
        }
        __syncthreads();
        #pragma unroll
        for (int kc = 0; kc < 4; ++kc) {
            const short8v tfr = lds_rd128(tls, arow, kc * 64 + lg * 16);
            #pragma unroll
            for (int ct = 0; ct < 8; ++ct) {
                const short8v b = *reinterpret_cast<const short8v*>(
                    W2T + (size_t)(ct * 16 + l15) * FFD + chunk * 128 + kc * 32 + lg * 8);
                acc3[ct] = __builtin_amdgcn_mfma_f32_16x16x32_bf16(tfr, b, acc3[ct], 0, 0, 0);
            }
        }
        __syncthreads();
    }

    #pragma unroll
    for (int ct = 0; ct < 8; ++ct) {
        const int col = ct * 16 + l15;
        const float b2v = b2[col];
        #pragma unroll
        for (int i = 0; i < 4; ++i) {
            const int node = nb + w * 16 + r0 + i;
            if (node < N_NODES) {
                const float f = (acc3[ct][i] + b2v) * mk[i];
                outp[(size_t)node * DIM + col] = xg[(size_t)node * DIM + col] + f;
            }
        }
    }
}

// ---------------------------------------------------------------------------
extern "C" void kernel_launch(void* const* d_in, const int* in_sizes, int n_in,
                              void* d_out, int out_size, void* d_ws, size_t ws_size,
                              hipStream_t stream)
{
    const float* node_rep = (const float*)d_in[0];
    const float* mask     = (const float*)d_in[1];
    const float* edge_feat= (const float*)d_in[2];
    const float* Wq = (const float*)d_in[3];
    const float* bq = (const float*)d_in[4];
    const float* Wk = (const float*)d_in[5];
    const float* bk = (const float*)d_in[6];
    const float* Wv = (const float*)d_in[7];
    const float* bv = (const float*)d_in[8];
    const float* Wo = (const float*)d_in[9];
    const float* bo = (const float*)d_in[10];
    const float* ln1_s = (const float*)d_in[11];
    const float* ln1_b = (const float*)d_in[12];
    const float* ln2_s = (const float*)d_in[13];
    const float* ln2_b = (const float*)d_in[14];
    const float* W1 = (const float*)d_in[15];
    const float* b1 = (const float*)d_in[16];
    const float* W2 = (const float*)d_in[17];
    const float* b2 = (const float*)d_in[18];
    const int* senders = (const int*)d_in[19];

    float* out = (float*)d_out;
    float* xg = (float*)d_ws;                           // [N,128] f32
    float* qg = xg + (size_t)N_NODES * DIM;             // [N,128] f32
    float* og = qg + (size_t)N_NODES * DIM;             // [N,128] f32
    unsigned short* Pp    = (unsigned short*)(og + (size_t)N_NODES * DIM);  // [N,256] bf16
    unsigned short* WkvTf = Pp + (size_t)N_NODES * 256;  // [32 frag][512]
    unsigned short* WoT   = WkvTf + 256 * 64;            // [128,128]
    unsigned short* W1T   = WoT + 128 * 128;             // [512,128]
    unsigned short* W2T   = W1T + 512 * 128;             // [128,512]

    hipLaunchKernelGGL(k0_prep, dim3(640), dim3(256), 0, stream,
                       Wk, Wv, Wo, W1, W2, WkvTf, WoT, W1T, W2T);
    hipLaunchKernelGGL(k1_ln_q_p, dim3(N_NODES / 8), dim3(256), 0, stream,
                       node_rep, mask, ln1_s, ln1_b, Wq, bq, Wk, bk, Wv, bv,
                       xg, qg, Pp);
    hipLaunchKernelGGL(k2_attn, dim3(N_NODES / 4), dim3(256), 0, stream,
                       qg, edge_feat, Pp, WkvTf, senders, og);
    hipLaunchKernelGGL(k3_ffn, dim3((N_NODES + 63) / 64), dim3(256), 0, stream,
                       og, xg, mask, WoT, bo, ln2_s, ln2_b, W1T, b1, W2T, b2, out);
}

// Round 15
// 253.900 us; speedup vs baseline: 1.0819x; 1.0819x over previous
//
#include <hip/hip_runtime.h>
#include <math.h>

#define N_NODES 20000
#define KNBR 32
#define DIM 128
#define EDIM 64
#define HEADS 8
#define OUTD 128
#define FFD 512
#define LN_EPS 1e-5f

typedef __attribute__((ext_vector_type(8))) short short8v;
typedef __attribute__((ext_vector_type(4))) float f32x4;

__device__ __forceinline__ unsigned short f2bf(float f) {
    unsigned u = __builtin_bit_cast(unsigned, f);
    u += 0x7fffu + ((u >> 16) & 1u);
    return (unsigned short)(u >> 16);
}
__device__ __forceinline__ float bfhi2f(unsigned u_hi16) {
    return __builtin_bit_cast(float, u_hi16);
}

// pack 8 f32 -> 8 bf16 via the proven scalar path
__device__ __forceinline__ short8v pack8(const float4 a, const float4 b) {
    short8v r;
    r[0] = (short)f2bf(a.x); r[1] = (short)f2bf(a.y);
    r[2] = (short)f2bf(a.z); r[3] = (short)f2bf(a.w);
    r[4] = (short)f2bf(b.x); r[5] = (short)f2bf(b.y);
    r[6] = (short)f2bf(b.z); r[7] = (short)f2bf(b.w);
    return r;
}

// DPP 16-lane all-lanes sum (VALU only, no DS)
template <int CTRL>
__device__ __forceinline__ float dpp_addf(float x) {
    const int s = __builtin_bit_cast(int, x);
    const int p = __builtin_amdgcn_update_dpp(s, s, CTRL, 0xF, 0xF, true);
    return x + __builtin_bit_cast(float, p);
}
__device__ __forceinline__ float red16(float x) {
    x = dpp_addf<0xB1>(x);
    x = dpp_addf<0x4E>(x);
    x = dpp_addf<0x141>(x);
    x = dpp_addf<0x140>(x);
    return x;
}

// ---------------------------------------------------------------------------
// K0: weight prep (round-7 proven version).
// ---------------------------------------------------------------------------
__global__ __launch_bounds__(256) void k0_prep(
    const float* __restrict__ Wk, const float* __restrict__ Wv,
    const float* __restrict__ Wo, const float* __restrict__ W1,
    const float* __restrict__ W2,
    unsigned short* __restrict__ WkvTf, unsigned short* __restrict__ WoT,
    unsigned short* __restrict__ W1T, unsigned short* __restrict__ W2T)
{
    const int idx = blockIdx.x * 256 + threadIdx.x;   // 163840 total
    if (idx < 16384) {
        const int frag = idx >> 9;          // cc*2 + s
        const int e    = idx & 511;
        const int lane = e >> 3, j = e & 7;
        const int cc = frag >> 1, s = frag & 1;
        const int c  = cc * 16 + (lane & 15);
        const int m  = s * 32 + (lane >> 4) * 8 + j;
        WkvTf[idx] = f2bf((c < 128) ? Wk[(size_t)(128 + m) * 128 + c]
                                    : Wv[(size_t)(128 + m) * 128 + (c - 128)]);
    } else if (idx < 32768) {
        const int j = idx - 16384, c = j >> 7, d = j & 127;
        WoT[j] = f2bf(Wo[(size_t)d * 128 + c]);
    } else if (idx < 98304) {
        const int j = idx - 32768, f = j >> 7, d = j & 127;
        W1T[j] = f2bf(W1[(size_t)d * 512 + f]);
    } else {
        const int j = idx - 98304, c = j >> 9, f = j & 511;
        W2T[j] = f2bf(W2[(size_t)f * 128 + c]);
    }
}

// ---------------------------------------------------------------------------
// K1: scalar f32 (proven numerics), LDS reads vectorized to ds_read_b128.
//   Per-accumulator accumulation order identical to round 7 -> bit-identical.
// ---------------------------------------------------------------------------
__global__ __launch_bounds__(256) void k1_ln_q_p(
    const float* __restrict__ node_rep, const float* __restrict__ mask,
    const float* __restrict__ ln1_s, const float* __restrict__ ln1_b,
    const float* __restrict__ Wq, const float* __restrict__ bq,
    const float* __restrict__ Wk, const float* __restrict__ bk,
    const float* __restrict__ Wv, const float* __restrict__ bv,
    float* __restrict__ xout, float* __restrict__ qout,
    unsigned short* __restrict__ Pp)
{
    __shared__ float xs[8][DIM];
    const int t = threadIdx.x;
    const int nb = blockIdx.x * 8;
    const int g = t >> 5;
    const int lane = t & 31;
    const int node = nb + g;

    float4 v = reinterpret_cast<const float4*>(node_rep + (size_t)node * DIM)[lane];
    float s1 = v.x + v.y + v.z + v.w;
    float s2 = v.x * v.x + v.y * v.y + v.z * v.z + v.w * v.w;
    #pragma unroll
    for (int off = 16; off; off >>= 1) {
        s1 += __shfl_xor(s1, off, 32);
        s2 += __shfl_xor(s2, off, 32);
    }
    const float mean = s1 * (1.0f / DIM);
    const float var  = s2 * (1.0f / DIM) - mean * mean;
    const float rs   = rsqrtf(var + LN_EPS);
    const float mk   = mask[node];

    float4 sc = reinterpret_cast<const float4*>(ln1_s)[lane];
    float4 of = reinterpret_cast<const float4*>(ln1_b)[lane];
    float4 xo;
    xo.x = ((v.x - mean) * rs * sc.x + of.x) * mk;
    xo.y = ((v.y - mean) * rs * sc.y + of.y) * mk;
    xo.z = ((v.z - mean) * rs * sc.z + of.z) * mk;
    xo.w = ((v.w - mean) * rs * sc.w + of.w) * mk;
    reinterpret_cast<float4*>(xout + (size_t)node * DIM)[lane] = xo;
    const int c0 = lane * 4;
    xs[g][c0 + 0] = xo.x; xs[g][c0 + 1] = xo.y;
    xs[g][c0 + 2] = xo.z; xs[g][c0 + 3] = xo.w;
    __syncthreads();

    const int col = t & 127;
    const int n0  = t >> 7;              // wave-uniform (waves 0,1 -> 0; 2,3 -> 1)
    const int c = t;
    const float* wq = Wq + col;
    const float* wp = (c < 128) ? (Wk + c) : (Wv + (c - 128));

    float accq[4] = {0.f, 0.f, 0.f, 0.f};
    float accp[8] = {0.f, 0.f, 0.f, 0.f, 0.f, 0.f, 0.f, 0.f};
    for (int d = 0; d < DIM; d += 4) {
        const float w0 = wq[(size_t)(d + 0) * 128];
        const float w1 = wq[(size_t)(d + 1) * 128];
        const float w2 = wq[(size_t)(d + 2) * 128];
        const float w3 = wq[(size_t)(d + 3) * 128];
        const float p0 = wp[(size_t)(d + 0) * 128];
        const float p1 = wp[(size_t)(d + 1) * 128];
        const float p2 = wp[(size_t)(d + 2) * 128];
        const float p3 = wp[(size_t)(d + 3) * 128];
        float4 xv[8];
        #pragma unroll
        for (int i = 0; i < 8; ++i)
            xv[i] = *reinterpret_cast<const float4*>(&xs[i][d]);
        #pragma unroll
        for (int i = 0; i < 8; ++i) {
            accp[i] += xv[i].x * p0;
            accp[i] += xv[i].y * p1;
            accp[i] += xv[i].z * p2;
            accp[i] += xv[i].w * p3;
        }
        if (n0 == 0) {
            #pragma unroll
            for (int i = 0; i < 4; ++i) {
                accq[i] += xv[2 * i].x * w0;
                accq[i] += xv[2 * i].y * w1;
                accq[i] += xv[2 * i].z * w2;
                accq[i] += xv[2 * i].w * w3;
            }
        } else {
            #pragma unroll
            for (int i = 0; i < 4; ++i) {
                accq[i] += xv[2 * i + 1].x * w0;
                accq[i] += xv[2 * i + 1].y * w1;
                accq[i] += xv[2 * i + 1].z * w2;
                accq[i] += xv[2 * i + 1].w * w3;
            }
        }
    }
    const float bqv = bq[col];
    #pragma unroll
    for (int i = 0; i < 4; ++i)
        qout[(size_t)(nb + n0 + 2 * i) * DIM + col] = accq[i] + bqv;

    const float bpv = (c < 128) ? bk[c] : bv[c - 128];
    #pragma unroll
    for (int i = 0; i < 8; ++i)
        Pp[(size_t)(nb + i) * 256 + c] = f2bf(accp[i] + bpv);
}

// ---------------------------------------------------------------------------
// K2 (round-14 proven): phase-split, attn weights via LDS, 4 waves/SIMD.
// ---------------------------------------------------------------------------
__global__ __launch_bounds__(256, 4) void k2_attn(
    const float* __restrict__ qg, const float* __restrict__ edge_feat,
    const unsigned short* __restrict__ Pp,
    const unsigned short* __restrict__ WkvTf,
    const int* __restrict__ senders,
    float* __restrict__ og)
{
    __shared__ unsigned attls[4][8][4][4];   // [wave][head][lg][j], 2 KB

    const int t = threadIdx.x;
    const int w = t >> 6, l = t & 63;
    const int n = blockIdx.x * 4 + w;
    const int l15 = l & 15, lg = l >> 4;

    const int s0 = senders[n * KNBR + l15];
    const int s1 = senders[n * KNBR + 16 + l15];

    short8v ib1, ib2;
    #pragma unroll
    for (int j = 0; j < 8; ++j) {
        const int m = lg * 8 + j;
        ib1[j] = (m == l15)      ? (short)0x3F80 : (short)0;
        ib2[j] = (m == l15 + 16) ? (short)0x3F80 : (short)0;
    }

    // ---- phase A: kk (cols 0..127) ----
    short8v afr[2][2];
    #pragma unroll
    for (int r = 0; r < 2; ++r) {
        #pragma unroll
        for (int s = 0; s < 2; ++s) {
            const float* ep = edge_feat
                + ((size_t)n * KNBR + 16 * r + l15) * EDIM + s * 32 + lg * 8;
            const float4 e0 = *reinterpret_cast<const float4*>(ep);
            const float4 e1 = *reinterpret_cast<const float4*>(ep + 4);
            afr[r][s] = pack8(e0, e1);
        }
    }

    f32x4 acc[2][8];
    #pragma unroll
    for (int r = 0; r < 2; ++r)
        #pragma unroll
        for (int cc = 0; cc < 8; ++cc)
            acc[r][cc] = (f32x4){0.f, 0.f, 0.f, 0.f};

    #pragma unroll
    for (int cc = 0; cc < 8; ++cc) {
        #pragma unroll
        for (int s = 0; s < 2; ++s) {
            const short8v b = *reinterpret_cast<const short8v*>(
                WkvTf + (((size_t)(cc * 2 + s)) << 9) + l * 8);
            acc[0][cc] = __builtin_amdgcn_mfma_f32_16x16x32_bf16(
                afr[0][s], b, acc[0][cc], 0, 0, 0);
            acc[1][cc] = __builtin_amdgcn_mfma_f32_16x16x32_bf16(
                afr[1][s], b, acc[1][cc], 0, 0, 0);
        }
    }
    #pragma unroll
    for (int c2 = 0; c2 < 4; ++c2) {
        const short8v pa0 = *reinterpret_cast<const short8v*>(
            Pp + (size_t)s0 * 256 + c2 * 32 + lg * 8);
        const short8v pa1 = *reinterpret_cast<const short8v*>(
            Pp + (size_t)s1 * 256 + c2 * 32 + lg * 8);
        acc[0][2 * c2]     = __builtin_amdgcn_mfma_f32_16x16x32_bf16(
            pa0, ib1, acc[0][2 * c2], 0, 0, 0);
        acc[0][2 * c2 + 1] = __builtin_amdgcn_mfma_f32_16x16x32_bf16(
            pa0, ib2, acc[0][2 * c2 + 1], 0, 0, 0);
        acc[1][2 * c2]     = __builtin_amdgcn_mfma_f32_16x16x32_bf16(
            pa1, ib1, acc[1][2 * c2], 0, 0, 0);
        acc[1][2 * c2 + 1] = __builtin_amdgcn_mfma_f32_16x16x32_bf16(
            pa1, ib2, acc[1][2 * c2 + 1], 0, 0, 0);
    }

    // logits -> softmax -> attn weights (x 1/s) -> bf16 packed -> LDS
    #pragma unroll
    for (int h = 0; h < 8; ++h) {
        const float qv = qg[(size_t)n * DIM + h * 16 + l15];
        float tm[8];
        #pragma unroll
        for (int r = 0; r < 2; ++r)
            #pragma unroll
            for (int i = 0; i < 4; ++i)
                tm[r * 4 + i] = acc[r][h][i] * qv;
        #pragma unroll
        for (int k = 0; k < 8; ++k) tm[k] = red16(tm[k]);
        float m = tm[0];
        #pragma unroll
        for (int k = 1; k < 8; ++k) m = fmaxf(m, tm[k]);
        m = fmaxf(m, __shfl_xor(m, 16, 64));
        m = fmaxf(m, __shfl_xor(m, 32, 64));
        float s = 0.f;
        #pragma unroll
        for (int k = 0; k < 8; ++k) {
            tm[k] = __expf((tm[k] - m) * 0.25f);
            s += tm[k];
        }
        s += __shfl_xor(s, 16, 64);
        s += __shfl_xor(s, 32, 64);
        const float inv = 1.0f / s;
        uint4 ap;
        ap.x = (unsigned)f2bf(tm[0] * inv) | ((unsigned)f2bf(tm[1] * inv) << 16);
        ap.y = (unsigned)f2bf(tm[2] * inv) | ((unsigned)f2bf(tm[3] * inv) << 16);
        ap.z = (unsigned)f2bf(tm[4] * inv) | ((unsigned)f2bf(tm[5] * inv) << 16);
        ap.w = (unsigned)f2bf(tm[6] * inv) | ((unsigned)f2bf(tm[7] * inv) << 16);
        if (l15 == 0)
            *reinterpret_cast<uint4*>(&attls[w][h][lg][0]) = ap;
    }

    // ---- phase B: vv (cols 128..255), acc + afr registers reused ----
    #pragma unroll
    for (int r = 0; r < 2; ++r) {
        #pragma unroll
        for (int s = 0; s < 2; ++s) {
            const float* ep = edge_feat
                + ((size_t)n * KNBR + 16 * r + l15) * EDIM + s * 32 + lg * 8;
            const float4 e0 = *reinterpret_cast<const float4*>(ep);
            const float4 e1 = *reinterpret_cast<const float4*>(ep + 4);
            afr[r][s] = pack8(e0, e1);
        }
    }

    #pragma unroll
    for (int r = 0; r < 2; ++r)
        #pragma unroll
        for (int cc = 0; cc < 8; ++cc)
            acc[r][cc] = (f32x4){0.f, 0.f, 0.f, 0.f};

    #pragma unroll
    for (int cc = 0; cc < 8; ++cc) {
        #pragma unroll
        for (int s = 0; s < 2; ++s) {
            const short8v b = *reinterpret_cast<const short8v*>(
                WkvTf + (((size_t)((8 + cc) * 2 + s)) << 9) + l * 8);
            acc[0][cc] = __builtin_amdgcn_mfma_f32_16x16x32_bf16(
                afr[0][s], b, acc[0][cc], 0, 0, 0);
            acc[1][cc] = __builtin_amdgcn_mfma_f32_16x16x32_bf16(
                afr[1][s], b, acc[1][cc], 0, 0, 0);
        }
    }
    #pragma unroll
    for (int c2 = 0; c2 < 4; ++c2) {
        const short8v pa0 = *reinterpret_cast<const short8v*>(
            Pp + (size_t)s0 * 256 + 128 + c2 * 32 + lg * 8);
        const short8v pa1 = *reinterpret_cast<const short8v*>(
            Pp + (size_t)s1 * 256 + 128 + c2 * 32 + lg * 8);
        acc[0][2 * c2]     = __builtin_amdgcn_mfma_f32_16x16x32_bf16(
            pa0, ib1, acc[0][2 * c2], 0, 0, 0);
        acc[0][2 * c2 + 1] = __builtin_amdgcn_mfma_f32_16x16x32_bf16(
            pa0, ib2, acc[0][2 * c2 + 1], 0, 0, 0);
        acc[1][2 * c2]     = __builtin_amdgcn_mfma_f32_16x16x32_bf16(
            pa1, ib1, acc[1][2 * c2], 0, 0, 0);
        acc[1][2 * c2 + 1] = __builtin_amdgcn_mfma_f32_16x16x32_bf16(
            pa1, ib2, acc[1][2 * c2 + 1], 0, 0, 0);
    }

    // PV per head: attn weights (incl. 1/s) read back from LDS (broadcast)
    #pragma unroll
    for (int h = 0; h < 8; ++h) {
        const uint4 ap = *reinterpret_cast<const uint4*>(&attls[w][h][lg][0]);
        float ov = 0.f;
        ov += bfhi2f(ap.x << 16)         * acc[0][h][0];
        ov += bfhi2f(ap.x & 0xffff0000u) * acc[0][h][1];
        ov += bfhi2f(ap.y << 16)         * acc[0][h][2];
        ov += bfhi2f(ap.y & 0xffff0000u) * acc[0][h][3];
        ov += bfhi2f(ap.z << 16)         * acc[1][h][0];
        ov += bfhi2f(ap.z & 0xffff0000u) * acc[1][h][1];
        ov += bfhi2f(ap.w << 16)         * acc[1][h][2];
        ov += bfhi2f(ap.w & 0xffff0000u) * acc[1][h][3];
        ov += __shfl_xor(ov, 16, 64);
        ov += __shfl_xor(ov, 32, 64);
        if (lg == 0)
            og[(size_t)n * DIM + h * 16 + l15] = ov;
    }
}

// ---------------------------------------------------------------------------
// K3 (MFMA, proven)
// ---------------------------------------------------------------------------
__device__ __forceinline__ void lds_wr16(unsigned short* base, int row, int col,
                                         unsigned short v) {
    const int byte = row * 256 + (((col * 2) ^ ((row & 7) << 4)));
    *reinterpret_cast<unsigned short*>(reinterpret_cast<char*>(base) + byte) = v;
}
__device__ __forceinline__ short8v lds_rd128(const unsigned short* base, int row,
                                             int colbyte) {
    const int byte = row * 256 + ((colbyte) ^ ((row & 7) << 4));
    return *reinterpret_cast<const short8v*>(
        reinterpret_cast<const char*>(base) + byte);
}

__global__ __launch_bounds__(256) void k3_ffn(
    const float* __restrict__ og, const float* __restrict__ xg,
    const float* __restrict__ mask,
    const unsigned short* __restrict__ WoT, const float* __restrict__ bo,
    const float* __restrict__ ln2_s, const float* __restrict__ ln2_b,
    const unsigned short* __restrict__ W1T, const float* __restrict__ b1,
    const unsigned short* __restrict__ W2T, const float* __restrict__ b2,
    float* __restrict__ outp)
{
    __shared__ unsigned short hls[64 * 128];
    __shared__ unsigned short tls[64 * 128];

    const int t = threadIdx.x;
    const int w = t >> 6, l = t & 63;
    const int l15 = l & 15, lg = l >> 4;
    const int nb = blockIdx.x * 64;
    const int arow = w * 16 + l15;
    const int anode = nb + arow;
    const int r0 = lg * 4;

    float mk[4];
    #pragma unroll
    for (int i = 0; i < 4; ++i) {
        const int node = nb + w * 16 + r0 + i;
        mk[i] = (node < N_NODES) ? mask[node] : 0.f;
    }

    f32x4 acc1[8];
    #pragma unroll
    for (int ct = 0; ct < 8; ++ct) acc1[ct] = (f32x4){0.f, 0.f, 0.f, 0.f};
    #pragma unroll
    for (int kc = 0; kc < 4; ++kc) {
        short8v afr = {0, 0, 0, 0, 0, 0, 0, 0};
        if (anode < N_NODES) {
            const float* op = og + (size_t)anode * DIM + kc * 32 + lg * 8;
            const float4 e0 = *reinterpret_cast<const float4*>(op);
            const float4 e1 = *reinterpret_cast<const float4*>(op + 4);
            afr = pack8(e0, e1);
        }
        #pragma unroll
        for (int ct = 0; ct < 8; ++ct) {
            const short8v b = *reinterpret_cast<const short8v*>(
                WoT + (size_t)(ct * 16 + l15) * DIM + kc * 32 + lg * 8);
            acc1[ct] = __builtin_amdgcn_mfma_f32_16x16x32_bf16(afr, b, acc1[ct], 0, 0, 0);
        }
    }

    float s1[4] = {0.f, 0.f, 0.f, 0.f}, s2[4] = {0.f, 0.f, 0.f, 0.f};
    #pragma unroll
    for (int ct = 0; ct < 8; ++ct) {
        const float bov = bo[ct * 16 + l15];
        #pragma unroll
        for (int i = 0; i < 4; ++i) {
            const float v2 = (acc1[ct][i] + bov) * mk[i];
            acc1[ct][i] = v2;
            s1[i] += v2; s2[i] += v2 * v2;
        }
    }
    #pragma unroll
    for (int off = 1; off <= 8; off <<= 1) {
        #pragma unroll
        for (int i = 0; i < 4; ++i) {
            s1[i] += __shfl_xor(s1[i], off, 64);
            s2[i] += __shfl_xor(s2[i], off, 64);
        }
    }
    float mean[4], rsv[4];
    #pragma unroll
    for (int i = 0; i < 4; ++i) {
        mean[i] = s1[i] * (1.0f / OUTD);
        const float var = s2[i] * (1.0f / OUTD) - mean[i] * mean[i];
        rsv[i] = rsqrtf(var + LN_EPS);
    }
    #pragma unroll
    for (int ct = 0; ct < 8; ++ct) {
        const int col = ct * 16 + l15;
        const float sc = ln2_s[col], ofs = ln2_b[col];
        #pragma unroll
        for (int i = 0; i < 4; ++i) {
            const float h = (acc1[ct][i] - mean[i]) * rsv[i] * sc + ofs;
            lds_wr16(hls, w * 16 + r0 + i, col, f2bf(h));
        }
    }
    __syncthreads();

    short8v hfr[4];
    #pragma unroll
    for (int kc = 0; kc < 4; ++kc)
        hfr[kc] = lds_rd128(hls, arow, kc * 64 + lg * 16);

    f32x4 acc3[8];
    #pragma unroll
    for (int ct = 0; ct < 8; ++ct) acc3[ct] = (f32x4){0.f, 0.f, 0.f, 0.f};

    for (int chunk = 0; chunk < 4; ++chunk) {
        f32x4 acc2[8];
        #pragma unroll
        for (int ct = 0; ct < 8; ++ct) acc2[ct] = (f32x4){0.f, 0.f, 0.f, 0.f};
        #pragma unroll
        for (int kc = 0; kc < 4; ++kc) {
            #pragma unroll
            for (int ct = 0; ct < 8; ++ct) {
                const short8v b = *reinterpret_cast<const short8v*>(
                    W1T + (size_t)(chunk * 128 + ct * 16 + l15) * DIM + kc * 32 + lg * 8);
                acc2[ct] = __builtin_amdgcn_mfma_f32_16x16x32_bf16(hfr[kc], b, acc2[ct], 0, 0, 0);
            }
        }
        #pragma unroll
        for (int ct = 0; ct < 8; ++ct) {
            const float bv = b1[chunk * 128 + ct * 16 + l15];
            #pragma unroll
            for (int i = 0; i < 4; ++i) {
                const float tv = fmaxf(acc2[ct][i] + bv, 0.f);
                lds_wr16(tls, w * 16 + r0 + i, ct * 16 + l15, f2bf(tv));
            }
        }
        __syncthreads();
        #pragma unroll
        for (int kc = 0; kc < 4; ++kc) {
            const short8v tfr = lds_rd128(tls, arow, kc * 64 + lg * 16);
            #pragma unroll
            for (int ct = 0; ct < 8; ++ct) {
                const short8v b = *reinterpret_cast<const short8v*>(
                    W2T + (size_t)(ct * 16 + l15) * FFD + chunk * 128 + kc * 32 + lg * 8);
                acc3[ct] = __builtin_amdgcn_mfma_f32_16x16x32_bf16(tfr, b, acc3[ct], 0, 0, 0);
            }
        }
        __syncthreads();
    }

    #pragma unroll
    for (int ct = 0; ct < 8; ++ct) {
        const int col = ct * 16 + l15;
        const float b2v = b2[col];
        #pragma unroll
        for (int i = 0; i < 4; ++i) {
            const int node = nb + w * 16 + r0 + i;
            if (node < N_NODES) {
                const float f = (acc3[ct][i] + b2v) * mk[i];
                outp[(size_t)node * DIM + col] = xg[(size_t)node * DIM + col] + f;
            }
        }
    }
}

// ---------------------------------------------------------------------------
extern "C" void kernel_launch(void* const* d_in, const int* in_sizes, int n_in,
                              void* d_out, int out_size, void* d_ws, size_t ws_size,
                              hipStream_t stream)
{
    const float* node_rep = (const float*)d_in[0];
    const float* mask     = (const float*)d_in[1];
    const float* edge_feat= (const float*)d_in[2];
    const float* Wq = (const float*)d_in[3];
    const float* bq = (const float*)d_in[4];
    const float* Wk = (const float*)d_in[5];
    const float* bk = (const float*)d_in[6];
    const float* Wv = (const float*)d_in[7];
    const float* bv = (const float*)d_in[8];
    const float* Wo = (const float*)d_in[9];
    const float* bo = (const float*)d_in[10];
    const float* ln1_s = (const float*)d_in[11];
    const float* ln1_b = (const float*)d_in[12];
    const float* ln2_s = (const float*)d_in[13];
    const float* ln2_b = (const float*)d_in[14];
    const float* W1 = (const float*)d_in[15];
    const float* b1 = (const float*)d_in[16];
    const float* W2 = (const float*)d_in[17];
    const float* b2 = (const float*)d_in[18];
    const int* senders = (const int*)d_in[19];

    float* out = (float*)d_out;
    float* xg = (float*)d_ws;                           // [N,128] f32
    float* qg = xg + (size_t)N_NODES * DIM;             // [N,128] f32
    float* og = qg + (size_t)N_NODES * DIM;             // [N,128] f32
    unsigned short* Pp    = (unsigned short*)(og + (size_t)N_NODES * DIM);  // [N,256] bf16
    unsigned short* WkvTf = Pp + (size_t)N_NODES * 256;  // [32 frag][512]
    unsigned short* WoT   = WkvTf + 256 * 64;            // [128,128]
    unsigned short* W1T   = WoT + 128 * 128;             // [512,128]
    unsigned short* W2T   = W1T + 512 * 128;             // [128,512]

    hipLaunchKernelGGL(k0_prep, dim3(640), dim3(256), 0, stream,
                       Wk, Wv, Wo, W1, W2, WkvTf, WoT, W1T, W2T);
    hipLaunchKernelGGL(k1_ln_q_p, dim3(N_NODES / 8), dim3(256), 0, stream,
                       node_rep, mask, ln1_s, ln1_b, Wq, bq, Wk, bk, Wv, bv,
                       xg, qg, Pp);
    hipLaunchKernelGGL(k2_attn, dim3(N_NODES / 4), dim3(256), 0, stream,
                       qg, edge_feat, Pp, WkvTf, senders, og);
    hipLaunchKernelGGL(k3_ffn, dim3((N_NODES + 63) / 64), dim3(256), 0, stream,
                       og, xg, mask, WoT, bo, ln2_s, ln2_b, W1T, b1, W2T, b2, out);
}

// Round 16
// 229.979 us; speedup vs baseline: 1.1945x; 1.1040x over previous
//
#include <hip/hip_runtime.h>
#include <math.h>

#define N_NODES 20000
#define KNBR 32
#define DIM 128
#define EDIM 64
#define HEADS 8
#define OUTD 128
#define FFD 512
#define LN_EPS 1e-5f

typedef __attribute__((ext_vector_type(8))) short short8v;
typedef __attribute__((ext_vector_type(4))) float f32x4;

__device__ __forceinline__ unsigned short f2bf(float f) {
    unsigned u = __builtin_bit_cast(unsigned, f);
    u += 0x7fffu + ((u >> 16) & 1u);
    return (unsigned short)(u >> 16);
}
__device__ __forceinline__ float bfhi2f(unsigned u_hi16) {
    return __builtin_bit_cast(float, u_hi16);
}

// pack 8 f32 -> 8 bf16 via the proven scalar path
__device__ __forceinline__ short8v pack8(const float4 a, const float4 b) {
    short8v r;
    r[0] = (short)f2bf(a.x); r[1] = (short)f2bf(a.y);
    r[2] = (short)f2bf(a.z); r[3] = (short)f2bf(a.w);
    r[4] = (short)f2bf(b.x); r[5] = (short)f2bf(b.y);
    r[6] = (short)f2bf(b.z); r[7] = (short)f2bf(b.w);
    return r;
}

// DPP 16-lane all-lanes sum (VALU only, no DS)
template <int CTRL>
__device__ __forceinline__ float dpp_addf(float x) {
    const int s = __builtin_bit_cast(int, x);
    const int p = __builtin_amdgcn_update_dpp(s, s, CTRL, 0xF, 0xF, true);
    return x + __builtin_bit_cast(float, p);
}
__device__ __forceinline__ float red16(float x) {
    x = dpp_addf<0xB1>(x);
    x = dpp_addf<0x4E>(x);
    x = dpp_addf<0x141>(x);
    x = dpp_addf<0x140>(x);
    return x;
}

// ---------------------------------------------------------------------------
// K0: weight prep (round-7 proven version).
// ---------------------------------------------------------------------------
__global__ __launch_bounds__(256) void k0_prep(
    const float* __restrict__ Wk, const float* __restrict__ Wv,
    const float* __restrict__ Wo, const float* __restrict__ W1,
    const float* __restrict__ W2,
    unsigned short* __restrict__ WkvTf, unsigned short* __restrict__ WoT,
    unsigned short* __restrict__ W1T, unsigned short* __restrict__ W2T)
{
    const int idx = blockIdx.x * 256 + threadIdx.x;   // 163840 total
    if (idx < 16384) {
        const int frag = idx >> 9;          // cc*2 + s
        const int e    = idx & 511;
        const int lane = e >> 3, j = e & 7;
        const int cc = frag >> 1, s = frag & 1;
        const int c  = cc * 16 + (lane & 15);
        const int m  = s * 32 + (lane >> 4) * 8 + j;
        WkvTf[idx] = f2bf((c < 128) ? Wk[(size_t)(128 + m) * 128 + c]
                                    : Wv[(size_t)(128 + m) * 128 + (c - 128)]);
    } else if (idx < 32768) {
        const int j = idx - 16384, c = j >> 7, d = j & 127;
        WoT[j] = f2bf(Wo[(size_t)d * 128 + c]);
    } else if (idx < 98304) {
        const int j = idx - 32768, f = j >> 7, d = j & 127;
        W1T[j] = f2bf(W1[(size_t)d * 512 + f]);
    } else {
        const int j = idx - 98304, c = j >> 9, f = j & 511;
        W2T[j] = f2bf(W2[(size_t)f * 128 + c]);
    }
}

// ---------------------------------------------------------------------------
// K1 (round-15 proven): scalar f32, LDS reads vectorized to ds_read_b128.
// ---------------------------------------------------------------------------
__global__ __launch_bounds__(256) void k1_ln_q_p(
    const float* __restrict__ node_rep, const float* __restrict__ mask,
    const float* __restrict__ ln1_s, const float* __restrict__ ln1_b,
    const float* __restrict__ Wq, const float* __restrict__ bq,
    const float* __restrict__ Wk, const float* __restrict__ bk,
    const float* __restrict__ Wv, const float* __restrict__ bv,
    float* __restrict__ xout, float* __restrict__ qout,
    unsigned short* __restrict__ Pp)
{
    __shared__ float xs[8][DIM];
    const int t = threadIdx.x;
    const int nb = blockIdx.x * 8;
    const int g = t >> 5;
    const int lane = t & 31;
    const int node = nb + g;

    float4 v = reinterpret_cast<const float4*>(node_rep + (size_t)node * DIM)[lane];
    float s1 = v.x + v.y + v.z + v.w;
    float s2 = v.x * v.x + v.y * v.y + v.z * v.z + v.w * v.w;
    #pragma unroll
    for (int off = 16; off; off >>= 1) {
        s1 += __shfl_xor(s1, off, 32);
        s2 += __shfl_xor(s2, off, 32);
    }
    const float mean = s1 * (1.0f / DIM);
    const float var  = s2 * (1.0f / DIM) - mean * mean;
    const float rs   = rsqrtf(var + LN_EPS);
    const float mk   = mask[node];

    float4 sc = reinterpret_cast<const float4*>(ln1_s)[lane];
    float4 of = reinterpret_cast<const float4*>(ln1_b)[lane];
    float4 xo;
    xo.x = ((v.x - mean) * rs * sc.x + of.x) * mk;
    xo.y = ((v.y - mean) * rs * sc.y + of.y) * mk;
    xo.z = ((v.z - mean) * rs * sc.z + of.z) * mk;
    xo.w = ((v.w - mean) * rs * sc.w + of.w) * mk;
    reinterpret_cast<float4*>(xout + (size_t)node * DIM)[lane] = xo;
    const int c0 = lane * 4;
    xs[g][c0 + 0] = xo.x; xs[g][c0 + 1] = xo.y;
    xs[g][c0 + 2] = xo.z; xs[g][c0 + 3] = xo.w;
    __syncthreads();

    const int col = t & 127;
    const int n0  = t >> 7;              // wave-uniform (waves 0,1 -> 0; 2,3 -> 1)
    const int c = t;
    const float* wq = Wq + col;
    const float* wp = (c < 128) ? (Wk + c) : (Wv + (c - 128));

    float accq[4] = {0.f, 0.f, 0.f, 0.f};
    float accp[8] = {0.f, 0.f, 0.f, 0.f, 0.f, 0.f, 0.f, 0.f};
    for (int d = 0; d < DIM; d += 4) {
        const float w0 = wq[(size_t)(d + 0) * 128];
        const float w1 = wq[(size_t)(d + 1) * 128];
        const float w2 = wq[(size_t)(d + 2) * 128];
        const float w3 = wq[(size_t)(d + 3) * 128];
        const float p0 = wp[(size_t)(d + 0) * 128];
        const float p1 = wp[(size_t)(d + 1) * 128];
        const float p2 = wp[(size_t)(d + 2) * 128];
        const float p3 = wp[(size_t)(d + 3) * 128];
        float4 xv[8];
        #pragma unroll
        for (int i = 0; i < 8; ++i)
            xv[i] = *reinterpret_cast<const float4*>(&xs[i][d]);
        #pragma unroll
        for (int i = 0; i < 8; ++i) {
            accp[i] += xv[i].x * p0;
            accp[i] += xv[i].y * p1;
            accp[i] += xv[i].z * p2;
            accp[i] += xv[i].w * p3;
        }
        if (n0 == 0) {
            #pragma unroll
            for (int i = 0; i < 4; ++i) {
                accq[i] += xv[2 * i].x * w0;
                accq[i] += xv[2 * i].y * w1;
                accq[i] += xv[2 * i].z * w2;
                accq[i] += xv[2 * i].w * w3;
            }
        } else {
            #pragma unroll
            for (int i = 0; i < 4; ++i) {
                accq[i] += xv[2 * i + 1].x * w0;
                accq[i] += xv[2 * i + 1].y * w1;
                accq[i] += xv[2 * i + 1].z * w2;
                accq[i] += xv[2 * i + 1].w * w3;
            }
        }
    }
    const float bqv = bq[col];
    #pragma unroll
    for (int i = 0; i < 4; ++i)
        qout[(size_t)(nb + n0 + 2 * i) * DIM + col] = accq[i] + bqv;

    const float bpv = (c < 128) ? bk[c] : bv[c - 128];
    #pragma unroll
    for (int i = 0; i < 8; ++i)
        Pp[(size_t)(nb + i) * 256 + c] = f2bf(accp[i] + bpv);
}

// ---------------------------------------------------------------------------
// K2 (round-14 proven): phase-split, attn weights via LDS, 4 waves/SIMD.
// ---------------------------------------------------------------------------
__global__ __launch_bounds__(256, 4) void k2_attn(
    const float* __restrict__ qg, const float* __restrict__ edge_feat,
    const unsigned short* __restrict__ Pp,
    const unsigned short* __restrict__ WkvTf,
    const int* __restrict__ senders,
    float* __restrict__ og)
{
    __shared__ unsigned attls[4][8][4][4];   // [wave][head][lg][j], 2 KB

    const int t = threadIdx.x;
    const int w = t >> 6, l = t & 63;
    const int n = blockIdx.x * 4 + w;
    const int l15 = l & 15, lg = l >> 4;

    const int s0 = senders[n * KNBR + l15];
    const int s1 = senders[n * KNBR + 16 + l15];

    short8v ib1, ib2;
    #pragma unroll
    for (int j = 0; j < 8; ++j) {
        const int m = lg * 8 + j;
        ib1[j] = (m == l15)      ? (short)0x3F80 : (short)0;
        ib2[j] = (m == l15 + 16) ? (short)0x3F80 : (short)0;
    }

    // ---- phase A: kk (cols 0..127) ----
    short8v afr[2][2];
    #pragma unroll
    for (int r = 0; r < 2; ++r) {
        #pragma unroll
        for (int s = 0; s < 2; ++s) {
            const float* ep = edge_feat
                + ((size_t)n * KNBR + 16 * r + l15) * EDIM + s * 32 + lg * 8;
            const float4 e0 = *reinterpret_cast<const float4*>(ep);
            const float4 e1 = *reinterpret_cast<const float4*>(ep + 4);
            afr[r][s] = pack8(e0, e1);
        }
    }

    f32x4 acc[2][8];
    #pragma unroll
    for (int r = 0; r < 2; ++r)
        #pragma unroll
        for (int cc = 0; cc < 8; ++cc)
            acc[r][cc] = (f32x4){0.f, 0.f, 0.f, 0.f};

    #pragma unroll
    for (int cc = 0; cc < 8; ++cc) {
        #pragma unroll
        for (int s = 0; s < 2; ++s) {
            const short8v b = *reinterpret_cast<const short8v*>(
                WkvTf + (((size_t)(cc * 2 + s)) << 9) + l * 8);
            acc[0][cc] = __builtin_amdgcn_mfma_f32_16x16x32_bf16(
                afr[0][s], b, acc[0][cc], 0, 0, 0);
            acc[1][cc] = __builtin_amdgcn_mfma_f32_16x16x32_bf16(
                afr[1][s], b, acc[1][cc], 0, 0, 0);
        }
    }
    #pragma unroll
    for (int c2 = 0; c2 < 4; ++c2) {
        const short8v pa0 = *reinterpret_cast<const short8v*>(
            Pp + (size_t)s0 * 256 + c2 * 32 + lg * 8);
        const short8v pa1 = *reinterpret_cast<const short8v*>(
            Pp + (size_t)s1 * 256 + c2 * 32 + lg * 8);
        acc[0][2 * c2]     = __builtin_amdgcn_mfma_f32_16x16x32_bf16(
            pa0, ib1, acc[0][2 * c2], 0, 0, 0);
        acc[0][2 * c2 + 1] = __builtin_amdgcn_mfma_f32_16x16x32_bf16(
            pa0, ib2, acc[0][2 * c2 + 1], 0, 0, 0);
        acc[1][2 * c2]     = __builtin_amdgcn_mfma_f32_16x16x32_bf16(
            pa1, ib1, acc[1][2 * c2], 0, 0, 0);
        acc[1][2 * c2 + 1] = __builtin_amdgcn_mfma_f32_16x16x32_bf16(
            pa1, ib2, acc[1][2 * c2 + 1], 0, 0, 0);
    }

    // logits -> softmax -> attn weights (x 1/s) -> bf16 packed -> LDS
    #pragma unroll
    for (int h = 0; h < 8; ++h) {
        const float qv = qg[(size_t)n * DIM + h * 16 + l15];
        float tm[8];
        #pragma unroll
        for (int r = 0; r < 2; ++r)
            #pragma unroll
            for (int i = 0; i < 4; ++i)
                tm[r * 4 + i] = acc[r][h][i] * qv;
        #pragma unroll
        for (int k = 0; k < 8; ++k) tm[k] = red16(tm[k]);
        float m = tm[0];
        #pragma unroll
        for (int k = 1; k < 8; ++k) m = fmaxf(m, tm[k]);
        m = fmaxf(m, __shfl_xor(m, 16, 64));
        m = fmaxf(m, __shfl_xor(m, 32, 64));
        float s = 0.f;
        #pragma unroll
        for (int k = 0; k < 8; ++k) {
            tm[k] = __expf((tm[k] - m) * 0.25f);
            s += tm[k];
        }
        s += __shfl_xor(s, 16, 64);
        s += __shfl_xor(s, 32, 64);
        const float inv = 1.0f / s;
        uint4 ap;
        ap.x = (unsigned)f2bf(tm[0] * inv) | ((unsigned)f2bf(tm[1] * inv) << 16);
        ap.y = (unsigned)f2bf(tm[2] * inv) | ((unsigned)f2bf(tm[3] * inv) << 16);
        ap.z = (unsigned)f2bf(tm[4] * inv) | ((unsigned)f2bf(tm[5] * inv) << 16);
        ap.w = (unsigned)f2bf(tm[6] * inv) | ((unsigned)f2bf(tm[7] * inv) << 16);
        if (l15 == 0)
            *reinterpret_cast<uint4*>(&attls[w][h][lg][0]) = ap;
    }

    // ---- phase B: vv (cols 128..255), acc + afr registers reused ----
    #pragma unroll
    for (int r = 0; r < 2; ++r) {
        #pragma unroll
        for (int s = 0; s < 2; ++s) {
            const float* ep = edge_feat
                + ((size_t)n * KNBR + 16 * r + l15) * EDIM + s * 32 + lg * 8;
            const float4 e0 = *reinterpret_cast<const float4*>(ep);
            const float4 e1 = *reinterpret_cast<const float4*>(ep + 4);
            afr[r][s] = pack8(e0, e1);
        }
    }

    #pragma unroll
    for (int r = 0; r < 2; ++r)
        #pragma unroll
        for (int cc = 0; cc < 8; ++cc)
            acc[r][cc] = (f32x4){0.f, 0.f, 0.f, 0.f};

    #pragma unroll
    for (int cc = 0; cc < 8; ++cc) {
        #pragma unroll
        for (int s = 0; s < 2; ++s) {
            const short8v b = *reinterpret_cast<const short8v*>(
                WkvTf + (((size_t)((8 + cc) * 2 + s)) << 9) + l * 8);
            acc[0][cc] = __builtin_amdgcn_mfma_f32_16x16x32_bf16(
                afr[0][s], b, acc[0][cc], 0, 0, 0);
            acc[1][cc] = __builtin_amdgcn_mfma_f32_16x16x32_bf16(
                afr[1][s], b, acc[1][cc], 0, 0, 0);
        }
    }
    #pragma unroll
    for (int c2 = 0; c2 < 4; ++c2) {
        const short8v pa0 = *reinterpret_cast<const short8v*>(
            Pp + (size_t)s0 * 256 + 128 + c2 * 32 + lg * 8);
        const short8v pa1 = *reinterpret_cast<const short8v*>(
            Pp + (size_t)s1 * 256 + 128 + c2 * 32 + lg * 8);
        acc[0][2 * c2]     = __builtin_amdgcn_mfma_f32_16x16x32_bf16(
            pa0, ib1, acc[0][2 * c2], 0, 0, 0);
        acc[0][2 * c2 + 1] = __builtin_amdgcn_mfma_f32_16x16x32_bf16(
            pa0, ib2, acc[0][2 * c2 + 1], 0, 0, 0);
        acc[1][2 * c2]     = __builtin_amdgcn_mfma_f32_16x16x32_bf16(
            pa1, ib1, acc[1][2 * c2], 0, 0, 0);
        acc[1][2 * c2 + 1] = __builtin_amdgcn_mfma_f32_16x16x32_bf16(
            pa1, ib2, acc[1][2 * c2 + 1], 0, 0, 0);
    }

    // PV per head: attn weights (incl. 1/s) read back from LDS (broadcast)
    #pragma unroll
    for (int h = 0; h < 8; ++h) {
        const uint4 ap = *reinterpret_cast<const uint4*>(&attls[w][h][lg][0]);
        float ov = 0.f;
        ov += bfhi2f(ap.x << 16)         * acc[0][h][0];
        ov += bfhi2f(ap.x & 0xffff0000u) * acc[0][h][1];
        ov += bfhi2f(ap.y << 16)         * acc[0][h][2];
        ov += bfhi2f(ap.y & 0xffff0000u) * acc[0][h][3];
        ov += bfhi2f(ap.z << 16)         * acc[1][h][0];
        ov += bfhi2f(ap.z & 0xffff0000u) * acc[1][h][1];
        ov += bfhi2f(ap.w << 16)         * acc[1][h][2];
        ov += bfhi2f(ap.w & 0xffff0000u) * acc[1][h][3];
        ov += __shfl_xor(ov, 16, 64);
        ov += __shfl_xor(ov, 32, 64);
        if (lg == 0)
            og[(size_t)n * DIM + h * 16 + l15] = ov;
    }
}

// ---------------------------------------------------------------------------
// K3 (MFMA): 1 WAVE PER BLOCK (16 nodes, 64 threads), grid 1250.
//   Waves never shared LDS rows -> all __syncthreads removed; same-wave
//   LDS RAW ordered by lgkmcnt; DS ops in-order per wave (tls WAR safe).
//   Math identical to the proven 4-wave version -> bit-identical output.
// ---------------------------------------------------------------------------
__device__ __forceinline__ void lds_wr16(unsigned short* base, int row, int col,
                                         unsigned short v) {
    const int byte = row * 256 + (((col * 2) ^ ((row & 7) << 4)));
    *reinterpret_cast<unsigned short*>(reinterpret_cast<char*>(base) + byte) = v;
}
__device__ __forceinline__ short8v lds_rd128(const unsigned short* base, int row,
                                             int colbyte) {
    const int byte = row * 256 + ((colbyte) ^ ((row & 7) << 4));
    return *reinterpret_cast<const short8v*>(
        reinterpret_cast<const char*>(base) + byte);
}

__global__ __launch_bounds__(64) void k3_ffn(
    const float* __restrict__ og, const float* __restrict__ xg,
    const float* __restrict__ mask,
    const unsigned short* __restrict__ WoT, const float* __restrict__ bo,
    const float* __restrict__ ln2_s, const float* __restrict__ ln2_b,
    const unsigned short* __restrict__ W1T, const float* __restrict__ b1,
    const unsigned short* __restrict__ W2T, const float* __restrict__ b2,
    float* __restrict__ outp)
{
    __shared__ unsigned short hls[16 * 128];
    __shared__ unsigned short tls[16 * 128];

    const int l = threadIdx.x;          // 0..63, one wave
    const int l15 = l & 15, lg = l >> 4;
    const int nb = blockIdx.x * 16;
    const int arow = l15;
    const int anode = nb + arow;
    const int r0 = lg * 4;

    float mk[4];
    #pragma unroll
    for (int i = 0; i < 4; ++i) {
        const int node = nb + r0 + i;
        mk[i] = (node < N_NODES) ? mask[node] : 0.f;
    }

    f32x4 acc1[8];
    #pragma unroll
    for (int ct = 0; ct < 8; ++ct) acc1[ct] = (f32x4){0.f, 0.f, 0.f, 0.f};
    #pragma unroll
    for (int kc = 0; kc < 4; ++kc) {
        short8v afr = {0, 0, 0, 0, 0, 0, 0, 0};
        if (anode < N_NODES) {
            const float* op = og + (size_t)anode * DIM + kc * 32 + lg * 8;
            const float4 e0 = *reinterpret_cast<const float4*>(op);
            const float4 e1 = *reinterpret_cast<const float4*>(op + 4);
            afr = pack8(e0, e1);
        }
        #pragma unroll
        for (int ct = 0; ct < 8; ++ct) {
            const short8v b = *reinterpret_cast<const short8v*>(
                WoT + (size_t)(ct * 16 + l15) * DIM + kc * 32 + lg * 8);
            acc1[ct] = __builtin_amdgcn_mfma_f32_16x16x32_bf16(afr, b, acc1[ct], 0, 0, 0);
        }
    }

    float s1[4] = {0.f, 0.f, 0.f, 0.f}, s2[4] = {0.f, 0.f, 0.f, 0.f};
    #pragma unroll
    for (int ct = 0; ct < 8; ++ct) {
        const float bov = bo[ct * 16 + l15];
        #pragma unroll
        for (int i = 0; i < 4; ++i) {
            const float v2 = (acc1[ct][i] + bov) * mk[i];
            acc1[ct][i] = v2;
            s1[i] += v2; s2[i] += v2 * v2;
        }
    }
    #pragma unroll
    for (int off = 1; off <= 8; off <<= 1) {
        #pragma unroll
        for (int i = 0; i < 4; ++i) {
            s1[i] += __shfl_xor(s1[i], off, 64);
            s2[i] += __shfl_xor(s2[i], off, 64);
        }
    }
    float mean[4], rsv[4];
    #pragma unroll
    for (int i = 0; i < 4; ++i) {
        mean[i] = s1[i] * (1.0f / OUTD);
        const float var = s2[i] * (1.0f / OUTD) - mean[i] * mean[i];
        rsv[i] = rsqrtf(var + LN_EPS);
    }
    #pragma unroll
    for (int ct = 0; ct < 8; ++ct) {
        const int col = ct * 16 + l15;
        const float sc = ln2_s[col], ofs = ln2_b[col];
        #pragma unroll
        for (int i = 0; i < 4; ++i) {
            const float h = (acc1[ct][i] - mean[i]) * rsv[i] * sc + ofs;
            lds_wr16(hls, r0 + i, col, f2bf(h));
        }
    }

    short8v hfr[4];
    #pragma unroll
    for (int kc = 0; kc < 4; ++kc)
        hfr[kc] = lds_rd128(hls, arow, kc * 64 + lg * 16);

    f32x4 acc3[8];
    #pragma unroll
    for (int ct = 0; ct < 8; ++ct) acc3[ct] = (f32x4){0.f, 0.f, 0.f, 0.f};

    for (int chunk = 0; chunk < 4; ++chunk) {
        f32x4 acc2[8];
        #pragma unroll
        for (int ct = 0; ct < 8; ++ct) acc2[ct] = (f32x4){0.f, 0.f, 0.f, 0.f};
        #pragma unroll
        for (int kc = 0; kc < 4; ++kc) {
            #pragma unroll
            for (int ct = 0; ct < 8; ++ct) {
                const short8v b = *reinterpret_cast<const short8v*>(
                    W1T + (size_t)(chunk * 128 + ct * 16 + l15) * DIM + kc * 32 + lg * 8);
                acc2[ct] = __builtin_amdgcn_mfma_f32_16x16x32_bf16(hfr[kc], b, acc2[ct], 0, 0, 0);
            }
        }
        #pragma unroll
        for (int ct = 0; ct < 8; ++ct) {
            const float bv = b1[chunk * 128 + ct * 16 + l15];
            #pragma unroll
            for (int i = 0; i < 4; ++i) {
                const float tv = fmaxf(acc2[ct][i] + bv, 0.f);
                lds_wr16(tls, r0 + i, ct * 16 + l15, f2bf(tv));
            }
        }
        #pragma unroll
        for (int kc = 0; kc < 4; ++kc) {
            const short8v tfr = lds_rd128(tls, arow, kc * 64 + lg * 16);
            #pragma unroll
            for (int ct = 0; ct < 8; ++ct) {
                const short8v b = *reinterpret_cast<const short8v*>(
                    W2T + (size_t)(ct * 16 + l15) * FFD + chunk * 128 + kc * 32 + lg * 8);
                acc3[ct] = __builtin_amdgcn_mfma_f32_16x16x32_bf16(tfr, b, acc3[ct], 0, 0, 0);
            }
        }
    }

    #pragma unroll
    for (int ct = 0; ct < 8; ++ct) {
        const int col = ct * 16 + l15;
        const float b2v = b2[col];
        #pragma unroll
        for (int i = 0; i < 4; ++i) {
            const int node = nb + r0 + i;
            if (node < N_NODES) {
                const float f = (acc3[ct][i] + b2v) * mk[i];
                outp[(size_t)node * DIM + col] = xg[(size_t)node * DIM + col] + f;
            }
        }
    }
}

// ---------------------------------------------------------------------------
extern "C" void kernel_launch(void* const* d_in, const int* in_sizes, int n_in,
                              void* d_out, int out_size, void* d_ws, size_t ws_size,
                              hipStream_t stream)
{
    const float* node_rep = (const float*)d_in[0];
    const float* mask     = (const float*)d_in[1];
    const float* edge_feat= (const float*)d_in[2];
    const float* Wq = (const float*)d_in[3];
    const float* bq = (const float*)d_in[4];
    const float* Wk = (const float*)d_in[5];
    const float* bk = (const float*)d_in[6];
    const float* Wv = (const float*)d_in[7];
    const float* bv = (const float*)d_in[8];
    const float* Wo = (const float*)d_in[9];
    const float* bo = (const float*)d_in[10];
    const float* ln1_s = (const float*)d_in[11];
    const float* ln1_b = (const float*)d_in[12];
    const float* ln2_s = (const float*)d_in[13];
    const float* ln2_b = (const float*)d_in[14];
    const float* W1 = (const float*)d_in[15];
    const float* b1 = (const float*)d_in[16];
    const float* W2 = (const float*)d_in[17];
    const float* b2 = (const float*)d_in[18];
    const int* senders = (const int*)d_in[19];

    float* out = (float*)d_out;
    float* xg = (float*)d_ws;                           // [N,128] f32
    float* qg = xg + (size_t)N_NODES * DIM;             // [N,128] f32
    float* og = qg + (size_t)N_NODES * DIM;             // [N,128] f32
    unsigned short* Pp    = (unsigned short*)(og + (size_t)N_NODES * DIM);  // [N,256] bf16
    unsigned short* WkvTf = Pp + (size_t)N_NODES * 256;  // [32 frag][512]
    unsigned short* WoT   = WkvTf + 256 * 64;            // [128,128]
    unsigned short* W1T   = WoT + 128 * 128;             // [512,128]
    unsigned short* W2T   = W1T + 512 * 128;             // [128,512]

    hipLaunchKernelGGL(k0_prep, dim3(640), dim3(256), 0, stream,
                       Wk, Wv, Wo, W1, W2, WkvTf, WoT, W1T, W2T);
    hipLaunchKernelGGL(k1_ln_q_p, dim3(N_NODES / 8), dim3(256), 0, stream,
                       node_rep, mask, ln1_s, ln1_b, Wq, bq, Wk, bk, Wv, bv,
                       xg, qg, Pp);
    hipLaunchKernelGGL(k2_attn, dim3(N_NODES / 4), dim3(256), 0, stream,
                       qg, edge_feat, Pp, WkvTf, senders, og);
    hipLaunchKernelGGL(k3_ffn, dim3((N_NODES + 15) / 16), dim3(64), 0, stream,
                       og, xg, mask, WoT, bo, ln2_s, ln2_b, W1T, b1, W2T, b2, out);
}

// Round 17
// 216.558 us; speedup vs baseline: 1.2685x; 1.0620x over previous
//
#include <hip/hip_runtime.h>
#include <math.h>

#define N_NODES 20000
#define KNBR 32
#define DIM 128
#define EDIM 64
#define HEADS 8
#define OUTD 128
#define FFD 512
#define LN_EPS 1e-5f

typedef __attribute__((ext_vector_type(8))) short short8v;
typedef __attribute__((ext_vector_type(4))) float f32x4;

__device__ __forceinline__ unsigned short f2bf(float f) {
    unsigned u = __builtin_bit_cast(unsigned, f);
    u += 0x7fffu + ((u >> 16) & 1u);
    return (unsigned short)(u >> 16);
}
__device__ __forceinline__ float bfhi2f(unsigned u_hi16) {
    return __builtin_bit_cast(float, u_hi16);
}

// pack 8 f32 -> 8 bf16 via the proven scalar path
__device__ __forceinline__ short8v pack8(const float4 a, const float4 b) {
    short8v r;
    r[0] = (short)f2bf(a.x); r[1] = (short)f2bf(a.y);
    r[2] = (short)f2bf(a.z); r[3] = (short)f2bf(a.w);
    r[4] = (short)f2bf(b.x); r[5] = (short)f2bf(b.y);
    r[6] = (short)f2bf(b.z); r[7] = (short)f2bf(b.w);
    return r;
}

// DPP 16-lane all-lanes sum (VALU only, no DS)
template <int CTRL>
__device__ __forceinline__ float dpp_addf(float x) {
    const int s = __builtin_bit_cast(int, x);
    const int p = __builtin_amdgcn_update_dpp(s, s, CTRL, 0xF, 0xF, true);
    return x + __builtin_bit_cast(float, p);
}
__device__ __forceinline__ float red16(float x) {
    x = dpp_addf<0xB1>(x);
    x = dpp_addf<0x4E>(x);
    x = dpp_addf<0x141>(x);
    x = dpp_addf<0x140>(x);
    return x;
}

// ---------------------------------------------------------------------------
// K0: weight prep (round-7 proven version).
// ---------------------------------------------------------------------------
__global__ __launch_bounds__(256) void k0_prep(
    const float* __restrict__ Wk, const float* __restrict__ Wv,
    const float* __restrict__ Wo, const float* __restrict__ W1,
    const float* __restrict__ W2,
    unsigned short* __restrict__ WkvTf, unsigned short* __restrict__ WoT,
    unsigned short* __restrict__ W1T, unsigned short* __restrict__ W2T)
{
    const int idx = blockIdx.x * 256 + threadIdx.x;   // 163840 total
    if (idx < 16384) {
        const int frag = idx >> 9;          // cc*2 + s
        const int e    = idx & 511;
        const int lane = e >> 3, j = e & 7;
        const int cc = frag >> 1, s = frag & 1;
        const int c  = cc * 16 + (lane & 15);
        const int m  = s * 32 + (lane >> 4) * 8 + j;
        WkvTf[idx] = f2bf((c < 128) ? Wk[(size_t)(128 + m) * 128 + c]
                                    : Wv[(size_t)(128 + m) * 128 + (c - 128)]);
    } else if (idx < 32768) {
        const int j = idx - 16384, c = j >> 7, d = j & 127;
        WoT[j] = f2bf(Wo[(size_t)d * 128 + c]);
    } else if (idx < 98304) {
        const int j = idx - 32768, f = j >> 7, d = j & 127;
        W1T[j] = f2bf(W1[(size_t)d * 512 + f]);
    } else {
        const int j = idx - 98304, c = j >> 9, f = j & 511;
        W2T[j] = f2bf(W2[(size_t)f * 128 + c]);
    }
}

// ---------------------------------------------------------------------------
// K1 (round-15 proven): scalar f32, LDS reads vectorized to ds_read_b128.
// ---------------------------------------------------------------------------
__global__ __launch_bounds__(256) void k1_ln_q_p(
    const float* __restrict__ node_rep, const float* __restrict__ mask,
    const float* __restrict__ ln1_s, const float* __restrict__ ln1_b,
    const float* __restrict__ Wq, const float* __restrict__ bq,
    const float* __restrict__ Wk, const float* __restrict__ bk,
    const float* __restrict__ Wv, const float* __restrict__ bv,
    float* __restrict__ xout, float* __restrict__ qout,
    unsigned short* __restrict__ Pp)
{
    __shared__ float xs[8][DIM];
    const int t = threadIdx.x;
    const int nb = blockIdx.x * 8;
    const int g = t >> 5;
    const int lane = t & 31;
    const int node = nb + g;

    float4 v = reinterpret_cast<const float4*>(node_rep + (size_t)node * DIM)[lane];
    float s1 = v.x + v.y + v.z + v.w;
    float s2 = v.x * v.x + v.y * v.y + v.z * v.z + v.w * v.w;
    #pragma unroll
    for (int off = 16; off; off >>= 1) {
        s1 += __shfl_xor(s1, off, 32);
        s2 += __shfl_xor(s2, off, 32);
    }
    const float mean = s1 * (1.0f / DIM);
    const float var  = s2 * (1.0f / DIM) - mean * mean;
    const float rs   = rsqrtf(var + LN_EPS);
    const float mk   = mask[node];

    float4 sc = reinterpret_cast<const float4*>(ln1_s)[lane];
    float4 of = reinterpret_cast<const float4*>(ln1_b)[lane];
    float4 xo;
    xo.x = ((v.x - mean) * rs * sc.x + of.x) * mk;
    xo.y = ((v.y - mean) * rs * sc.y + of.y) * mk;
    xo.z = ((v.z - mean) * rs * sc.z + of.z) * mk;
    xo.w = ((v.w - mean) * rs * sc.w + of.w) * mk;
    reinterpret_cast<float4*>(xout + (size_t)node * DIM)[lane] = xo;
    const int c0 = lane * 4;
    xs[g][c0 + 0] = xo.x; xs[g][c0 + 1] = xo.y;
    xs[g][c0 + 2] = xo.z; xs[g][c0 + 3] = xo.w;
    __syncthreads();

    const int col = t & 127;
    const int n0  = t >> 7;              // wave-uniform (waves 0,1 -> 0; 2,3 -> 1)
    const int c = t;
    const float* wq = Wq + col;
    const float* wp = (c < 128) ? (Wk + c) : (Wv + (c - 128));

    float accq[4] = {0.f, 0.f, 0.f, 0.f};
    float accp[8] = {0.f, 0.f, 0.f, 0.f, 0.f, 0.f, 0.f, 0.f};
    for (int d = 0; d < DIM; d += 4) {
        const float w0 = wq[(size_t)(d + 0) * 128];
        const float w1 = wq[(size_t)(d + 1) * 128];
        const float w2 = wq[(size_t)(d + 2) * 128];
        const float w3 = wq[(size_t)(d + 3) * 128];
        const float p0 = wp[(size_t)(d + 0) * 128];
        const float p1 = wp[(size_t)(d + 1) * 128];
        const float p2 = wp[(size_t)(d + 2) * 128];
        const float p3 = wp[(size_t)(d + 3) * 128];
        float4 xv[8];
        #pragma unroll
        for (int i = 0; i < 8; ++i)
            xv[i] = *reinterpret_cast<const float4*>(&xs[i][d]);
        #pragma unroll
        for (int i = 0; i < 8; ++i) {
            accp[i] += xv[i].x * p0;
            accp[i] += xv[i].y * p1;
            accp[i] += xv[i].z * p2;
            accp[i] += xv[i].w * p3;
        }
        if (n0 == 0) {
            #pragma unroll
            for (int i = 0; i < 4; ++i) {
                accq[i] += xv[2 * i].x * w0;
                accq[i] += xv[2 * i].y * w1;
                accq[i] += xv[2 * i].z * w2;
                accq[i] += xv[2 * i].w * w3;
            }
        } else {
            #pragma unroll
            for (int i = 0; i < 4; ++i) {
                accq[i] += xv[2 * i + 1].x * w0;
                accq[i] += xv[2 * i + 1].y * w1;
                accq[i] += xv[2 * i + 1].z * w2;
                accq[i] += xv[2 * i + 1].w * w3;
            }
        }
    }
    const float bqv = bq[col];
    #pragma unroll
    for (int i = 0; i < 4; ++i)
        qout[(size_t)(nb + n0 + 2 * i) * DIM + col] = accq[i] + bqv;

    const float bpv = (c < 128) ? bk[c] : bv[c - 128];
    #pragma unroll
    for (int i = 0; i < 8; ++i)
        Pp[(size_t)(nb + i) * 256 + c] = f2bf(accp[i] + bpv);
}

// ---------------------------------------------------------------------------
// K2: phase-split attention + WkvTf STAGED IN LDS (32 KB, same table every
//   block -> one coalesced stage + barrier; B-loads become conflict-free
//   ds_read_b128, vmcnt queue freed for edges + Pp gather).
// ---------------------------------------------------------------------------
__global__ __launch_bounds__(256, 4) void k2_attn(
    const float* __restrict__ qg, const float* __restrict__ edge_feat,
    const unsigned short* __restrict__ Pp,
    const unsigned short* __restrict__ WkvTf,
    const int* __restrict__ senders,
    float* __restrict__ og)
{
    __shared__ unsigned short wls[32 * 512];   // 32 KB, full WkvTf
    __shared__ unsigned attls[4][8][4][4];     // [wave][head][lg][j], 2 KB

    const int t = threadIdx.x;
    const int w = t >> 6, l = t & 63;
    const int n = blockIdx.x * 4 + w;
    const int l15 = l & 15, lg = l >> 4;

    // stage WkvTf -> LDS: 2048 uint4, 8 per thread, coalesced
    {
        const uint4* src = reinterpret_cast<const uint4*>(WkvTf);
        uint4* dst = reinterpret_cast<uint4*>(wls);
        #pragma unroll
        for (int i = 0; i < 8; ++i)
            dst[i * 256 + t] = src[i * 256 + t];
    }

    const int s0 = senders[n * KNBR + l15];
    const int s1 = senders[n * KNBR + 16 + l15];

    short8v ib1, ib2;
    #pragma unroll
    for (int j = 0; j < 8; ++j) {
        const int m = lg * 8 + j;
        ib1[j] = (m == l15)      ? (short)0x3F80 : (short)0;
        ib2[j] = (m == l15 + 16) ? (short)0x3F80 : (short)0;
    }

    // ---- phase A: kk (cols 0..127) ----
    short8v afr[2][2];
    #pragma unroll
    for (int r = 0; r < 2; ++r) {
        #pragma unroll
        for (int s = 0; s < 2; ++s) {
            const float* ep = edge_feat
                + ((size_t)n * KNBR + 16 * r + l15) * EDIM + s * 32 + lg * 8;
            const float4 e0 = *reinterpret_cast<const float4*>(ep);
            const float4 e1 = *reinterpret_cast<const float4*>(ep + 4);
            afr[r][s] = pack8(e0, e1);
        }
    }

    __syncthreads();   // wls ready

    f32x4 acc[2][8];
    #pragma unroll
    for (int r = 0; r < 2; ++r)
        #pragma unroll
        for (int cc = 0; cc < 8; ++cc)
            acc[r][cc] = (f32x4){0.f, 0.f, 0.f, 0.f};

    #pragma unroll
    for (int cc = 0; cc < 8; ++cc) {
        #pragma unroll
        for (int s = 0; s < 2; ++s) {
            const short8v b = *reinterpret_cast<const short8v*>(
                wls + ((cc * 2 + s) << 9) + l * 8);
            acc[0][cc] = __builtin_amdgcn_mfma_f32_16x16x32_bf16(
                afr[0][s], b, acc[0][cc], 0, 0, 0);
            acc[1][cc] = __builtin_amdgcn_mfma_f32_16x16x32_bf16(
                afr[1][s], b, acc[1][cc], 0, 0, 0);
        }
    }
    #pragma unroll
    for (int c2 = 0; c2 < 4; ++c2) {
        const short8v pa0 = *reinterpret_cast<const short8v*>(
            Pp + (size_t)s0 * 256 + c2 * 32 + lg * 8);
        const short8v pa1 = *reinterpret_cast<const short8v*>(
            Pp + (size_t)s1 * 256 + c2 * 32 + lg * 8);
        acc[0][2 * c2]     = __builtin_amdgcn_mfma_f32_16x16x32_bf16(
            pa0, ib1, acc[0][2 * c2], 0, 0, 0);
        acc[0][2 * c2 + 1] = __builtin_amdgcn_mfma_f32_16x16x32_bf16(
            pa0, ib2, acc[0][2 * c2 + 1], 0, 0, 0);
        acc[1][2 * c2]     = __builtin_amdgcn_mfma_f32_16x16x32_bf16(
            pa1, ib1, acc[1][2 * c2], 0, 0, 0);
        acc[1][2 * c2 + 1] = __builtin_amdgcn_mfma_f32_16x16x32_bf16(
            pa1, ib2, acc[1][2 * c2 + 1], 0, 0, 0);
    }

    // logits -> softmax -> attn weights (x 1/s) -> bf16 packed -> LDS
    #pragma unroll
    for (int h = 0; h < 8; ++h) {
        const float qv = qg[(size_t)n * DIM + h * 16 + l15];
        float tm[8];
        #pragma unroll
        for (int r = 0; r < 2; ++r)
            #pragma unroll
            for (int i = 0; i < 4; ++i)
                tm[r * 4 + i] = acc[r][h][i] * qv;
        #pragma unroll
        for (int k = 0; k < 8; ++k) tm[k] = red16(tm[k]);
        float m = tm[0];
        #pragma unroll
        for (int k = 1; k < 8; ++k) m = fmaxf(m, tm[k]);
        m = fmaxf(m, __shfl_xor(m, 16, 64));
        m = fmaxf(m, __shfl_xor(m, 32, 64));
        float s = 0.f;
        #pragma unroll
        for (int k = 0; k < 8; ++k) {
            tm[k] = __expf((tm[k] - m) * 0.25f);
            s += tm[k];
        }
        s += __shfl_xor(s, 16, 64);
        s += __shfl_xor(s, 32, 64);
        const float inv = 1.0f / s;
        uint4 ap;
        ap.x = (unsigned)f2bf(tm[0] * inv) | ((unsigned)f2bf(tm[1] * inv) << 16);
        ap.y = (unsigned)f2bf(tm[2] * inv) | ((unsigned)f2bf(tm[3] * inv) << 16);
        ap.z = (unsigned)f2bf(tm[4] * inv) | ((unsigned)f2bf(tm[5] * inv) << 16);
        ap.w = (unsigned)f2bf(tm[6] * inv) | ((unsigned)f2bf(tm[7] * inv) << 16);
        if (l15 == 0)
            *reinterpret_cast<uint4*>(&attls[w][h][lg][0]) = ap;
    }

    // ---- phase B: vv (cols 128..255), acc + afr registers reused ----
    #pragma unroll
    for (int r = 0; r < 2; ++r) {
        #pragma unroll
        for (int s = 0; s < 2; ++s) {
            const float* ep = edge_feat
                + ((size_t)n * KNBR + 16 * r + l15) * EDIM + s * 32 + lg * 8;
            const float4 e0 = *reinterpret_cast<const float4*>(ep);
            const float4 e1 = *reinterpret_cast<const float4*>(ep + 4);
            afr[r][s] = pack8(e0, e1);
        }
    }

    #pragma unroll
    for (int r = 0; r < 2; ++r)
        #pragma unroll
        for (int cc = 0; cc < 8; ++cc)
            acc[r][cc] = (f32x4){0.f, 0.f, 0.f, 0.f};

    #pragma unroll
    for (int cc = 0; cc < 8; ++cc) {
        #pragma unroll
        for (int s = 0; s < 2; ++s) {
            const short8v b = *reinterpret_cast<const short8v*>(
                wls + (((8 + cc) * 2 + s) << 9) + l * 8);
            acc[0][cc] = __builtin_amdgcn_mfma_f32_16x16x32_bf16(
                afr[0][s], b, acc[0][cc], 0, 0, 0);
            acc[1][cc] = __builtin_amdgcn_mfma_f32_16x16x32_bf16(
                afr[1][s], b, acc[1][cc], 0, 0, 0);
        }
    }
    #pragma unroll
    for (int c2 = 0; c2 < 4; ++c2) {
        const short8v pa0 = *reinterpret_cast<const short8v*>(
            Pp + (size_t)s0 * 256 + 128 + c2 * 32 + lg * 8);
        const short8v pa1 = *reinterpret_cast<const short8v*>(
            Pp + (size_t)s1 * 256 + 128 + c2 * 32 + lg * 8);
        acc[0][2 * c2]     = __builtin_amdgcn_mfma_f32_16x16x32_bf16(
            pa0, ib1, acc[0][2 * c2], 0, 0, 0);
        acc[0][2 * c2 + 1] = __builtin_amdgcn_mfma_f32_16x16x32_bf16(
            pa0, ib2, acc[0][2 * c2 + 1], 0, 0, 0);
        acc[1][2 * c2]     = __builtin_amdgcn_mfma_f32_16x16x32_bf16(
            pa1, ib1, acc[1][2 * c2], 0, 0, 0);
        acc[1][2 * c2 + 1] = __builtin_amdgcn_mfma_f32_16x16x32_bf16(
            pa1, ib2, acc[1][2 * c2 + 1], 0, 0, 0);
    }

    // PV per head: attn weights (incl. 1/s) read back from LDS (broadcast)
    #pragma unroll
    for (int h = 0; h < 8; ++h) {
        const uint4 ap = *reinterpret_cast<const uint4*>(&attls[w][h][lg][0]);
        float ov = 0.f;
        ov += bfhi2f(ap.x << 16)         * acc[0][h][0];
        ov += bfhi2f(ap.x & 0xffff0000u) * acc[0][h][1];
        ov += bfhi2f(ap.y << 16)         * acc[0][h][2];
        ov += bfhi2f(ap.y & 0xffff0000u) * acc[0][h][3];
        ov += bfhi2f(ap.z << 16)         * acc[1][h][0];
        ov += bfhi2f(ap.z & 0xffff0000u) * acc[1][h][1];
        ov += bfhi2f(ap.w << 16)         * acc[1][h][2];
        ov += bfhi2f(ap.w & 0xffff0000u) * acc[1][h][3];
        ov += __shfl_xor(ov, 16, 64);
        ov += __shfl_xor(ov, 32, 64);
        if (lg == 0)
            og[(size_t)n * DIM + h * 16 + l15] = ov;
    }
}

// ---------------------------------------------------------------------------
// K3 (round-16 proven): 1 wave per block (16 nodes), no barriers.
// ---------------------------------------------------------------------------
__device__ __forceinline__ void lds_wr16(unsigned short* base, int row, int col,
                                         unsigned short v) {
    const int byte = row * 256 + (((col * 2) ^ ((row & 7) << 4)));
    *reinterpret_cast<unsigned short*>(reinterpret_cast<char*>(base) + byte) = v;
}
__device__ __forceinline__ short8v lds_rd128(const unsigned short* base, int row,
                                             int colbyte) {
    const int byte = row * 256 + ((colbyte) ^ ((row & 7) << 4));
    return *reinterpret_cast<const short8v*>(
        reinterpret_cast<const char*>(base) + byte);
}

__global__ __launch_bounds__(64) void k3_ffn(
    const float* __restrict__ og, const float* __restrict__ xg,
    const float* __restrict__ mask,
    const unsigned short* __restrict__ WoT, const float* __restrict__ bo,
    const float* __restrict__ ln2_s, const float* __restrict__ ln2_b,
    const unsigned short* __restrict__ W1T, const float* __restrict__ b1,
    const unsigned short* __restrict__ W2T, const float* __restrict__ b2,
    float* __restrict__ outp)
{
    __shared__ unsigned short hls[16 * 128];
    __shared__ unsigned short tls[16 * 128];

    const int l = threadIdx.x;          // 0..63, one wave
    const int l15 = l & 15, lg = l >> 4;
    const int nb = blockIdx.x * 16;
    const int arow = l15;
    const int anode = nb + arow;
    const int r0 = lg * 4;

    float mk[4];
    #pragma unroll
    for (int i = 0; i < 4; ++i) {
        const int node = nb + r0 + i;
        mk[i] = (node < N_NODES) ? mask[node] : 0.f;
    }

    f32x4 acc1[8];
    #pragma unroll
    for (int ct = 0; ct < 8; ++ct) acc1[ct] = (f32x4){0.f, 0.f, 0.f, 0.f};
    #pragma unroll
    for (int kc = 0; kc < 4; ++kc) {
        short8v afr = {0, 0, 0, 0, 0, 0, 0, 0};
        if (anode < N_NODES) {
            const float* op = og + (size_t)anode * DIM + kc * 32 + lg * 8;
            const float4 e0 = *reinterpret_cast<const float4*>(op);
            const float4 e1 = *reinterpret_cast<const float4*>(op + 4);
            afr = pack8(e0, e1);
        }
        #pragma unroll
        for (int ct = 0; ct < 8; ++ct) {
            const short8v b = *reinterpret_cast<const short8v*>(
                WoT + (size_t)(ct * 16 + l15) * DIM + kc * 32 + lg * 8);
            acc1[ct] = __builtin_amdgcn_mfma_f32_16x16x32_bf16(afr, b, acc1[ct], 0, 0, 0);
        }
    }

    float s1[4] = {0.f, 0.f, 0.f, 0.f}, s2[4] = {0.f, 0.f, 0.f, 0.f};
    #pragma unroll
    for (int ct = 0; ct < 8; ++ct) {
        const float bov = bo[ct * 16 + l15];
        #pragma unroll
        for (int i = 0; i < 4; ++i) {
            const float v2 = (acc1[ct][i] + bov) * mk[i];
            acc1[ct][i] = v2;
            s1[i] += v2; s2[i] += v2 * v2;
        }
    }
    #pragma unroll
    for (int off = 1; off <= 8; off <<= 1) {
        #pragma unroll
        for (int i = 0; i < 4; ++i) {
            s1[i] += __shfl_xor(s1[i], off, 64);
            s2[i] += __shfl_xor(s2[i], off, 64);
        }
    }
    float mean[4], rsv[4];
    #pragma unroll
    for (int i = 0; i < 4; ++i) {
        mean[i] = s1[i] * (1.0f / OUTD);
        const float var = s2[i] * (1.0f / OUTD) - mean[i] * mean[i];
        rsv[i] = rsqrtf(var + LN_EPS);
    }
    #pragma unroll
    for (int ct = 0; ct < 8; ++ct) {
        const int col = ct * 16 + l15;
        const float sc = ln2_s[col], ofs = ln2_b[col];
        #pragma unroll
        for (int i = 0; i < 4; ++i) {
            const float h = (acc1[ct][i] - mean[i]) * rsv[i] * sc + ofs;
            lds_wr16(hls, r0 + i, col, f2bf(h));
        }
    }

    short8v hfr[4];
    #pragma unroll
    for (int kc = 0; kc < 4; ++kc)
        hfr[kc] = lds_rd128(hls, arow, kc * 64 + lg * 16);

    f32x4 acc3[8];
    #pragma unroll
    for (int ct = 0; ct < 8; ++ct) acc3[ct] = (f32x4){0.f, 0.f, 0.f, 0.f};

    for (int chunk = 0; chunk < 4; ++chunk) {
        f32x4 acc2[8];
        #pragma unroll
        for (int ct = 0; ct < 8; ++ct) acc2[ct] = (f32x4){0.f, 0.f, 0.f, 0.f};
        #pragma unroll
        for (int kc = 0; kc < 4; ++kc) {
            #pragma unroll
            for (int ct = 0; ct < 8; ++ct) {
                const short8v b = *reinterpret_cast<const short8v*>(
                    W1T + (size_t)(chunk * 128 + ct * 16 + l15) * DIM + kc * 32 + lg * 8);
                acc2[ct] = __builtin_amdgcn_mfma_f32_16x16x32_bf16(hfr[kc], b, acc2[ct], 0, 0, 0);
            }
        }
        #pragma unroll
        for (int ct = 0; ct < 8; ++ct) {
            const float bv = b1[chunk * 128 + ct * 16 + l15];
            #pragma unroll
            for (int i = 0; i < 4; ++i) {
                const float tv = fmaxf(acc2[ct][i] + bv, 0.f);
                lds_wr16(tls, r0 + i, ct * 16 + l15, f2bf(tv));
            }
        }
        #pragma unroll
        for (int kc = 0; kc < 4; ++kc) {
            const short8v tfr = lds_rd128(tls, arow, kc * 64 + lg * 16);
            #pragma unroll
            for (int ct = 0; ct < 8; ++ct) {
                const short8v b = *reinterpret_cast<const short8v*>(
                    W2T + (size_t)(ct * 16 + l15) * FFD + chunk * 128 + kc * 32 + lg * 8);
                acc3[ct] = __builtin_amdgcn_mfma_f32_16x16x32_bf16(tfr, b, acc3[ct], 0, 0, 0);
            }
        }
    }

    #pragma unroll
    for (int ct = 0; ct < 8; ++ct) {
        const int col = ct * 16 + l15;
        const float b2v = b2[col];
        #pragma unroll
        for (int i = 0; i < 4; ++i) {
            const int node = nb + r0 + i;
            if (node < N_NODES) {
                const float f = (acc3[ct][i] + b2v) * mk[i];
                outp[(size_t)node * DIM + col] = xg[(size_t)node * DIM + col] + f;
            }
        }
    }
}

// ---------------------------------------------------------------------------
extern "C" void kernel_launch(void* const* d_in, const int* in_sizes, int n_in,
                              void* d_out, int out_size, void* d_ws, size_t ws_size,
                              hipStream_t stream)
{
    const float* node_rep = (const float*)d_in[0];
    const float* mask     = (const float*)d_in[1];
    const float* edge_feat= (const float*)d_in[2];
    const float* Wq = (const float*)d_in[3];
    const float* bq = (const float*)d_in[4];
    const float* Wk = (const float*)d_in[5];
    const float* bk = (const float*)d_in[6];
    const float* Wv = (const float*)d_in[7];
    const float* bv = (const float*)d_in[8];
    const float* Wo = (const float*)d_in[9];
    const float* bo = (const float*)d_in[10];
    const float* ln1_s = (const float*)d_in[11];
    const float* ln1_b = (const float*)d_in[12];
    const float* ln2_s = (const float*)d_in[13];
    const float* ln2_b = (const float*)d_in[14];
    const float* W1 = (const float*)d_in[15];
    const float* b1 = (const float*)d_in[16];
    const float* W2 = (const float*)d_in[17];
    const float* b2 = (const float*)d_in[18];
    const int* senders = (const int*)d_in[19];

    float* out = (float*)d_out;
    float* xg = (float*)d_ws;                           // [N,128] f32
    float* qg = xg + (size_t)N_NODES * DIM;             // [N,128] f32
    float* og = qg + (size_t)N_NODES * DIM;             // [N,128] f32
    unsigned short* Pp    = (unsigned short*)(og + (size_t)N_NODES * DIM);  // [N,256] bf16
    unsigned short* WkvTf = Pp + (size_t)N_NODES * 256;  // [32 frag][512]
    unsigned short* WoT   = WkvTf + 256 * 64;            // [128,128]
    unsigned short* W1T   = WoT + 128 * 128;             // [512,128]
    unsigned short* W2T   = W1T + 512 * 128;             // [128,512]

    hipLaunchKernelGGL(k0_prep, dim3(640), dim3(256), 0, stream,
                       Wk, Wv, Wo, W1, W2, WkvTf, WoT, W1T, W2T);
    hipLaunchKernelGGL(k1_ln_q_p, dim3(N_NODES / 8), dim3(256), 0, stream,
                       node_rep, mask, ln1_s, ln1_b, Wq, bq, Wk, bk, Wv, bv,
                       xg, qg, Pp);
    hipLaunchKernelGGL(k2_attn, dim3(N_NODES / 4), dim3(256), 0, stream,
                       qg, edge_feat, Pp, WkvTf, senders, og);
    hipLaunchKernelGGL(k3_ffn, dim3((N_NODES + 15) / 16), dim3(64), 0, stream,
                       og, xg, mask, WoT, bo, ln2_s, ln2_b, W1T, b1, W2T, b2, out);
}

// Round 18
// 212.155 us; speedup vs baseline: 1.2948x; 1.0208x over previous
//
#include <hip/hip_runtime.h>
#include <math.h>

#define N_NODES 20000
#define KNBR 32
#define DIM 128
#define EDIM 64
#define HEADS 8
#define OUTD 128
#define FFD 512
#define LN_EPS 1e-5f

typedef __attribute__((ext_vector_type(8))) short short8v;
typedef __attribute__((ext_vector_type(4))) float f32x4;

__device__ __forceinline__ unsigned short f2bf(float f) {
    unsigned u = __builtin_bit_cast(unsigned, f);
    u += 0x7fffu + ((u >> 16) & 1u);
    return (unsigned short)(u >> 16);
}
__device__ __forceinline__ float bfhi2f(unsigned u_hi16) {
    return __builtin_bit_cast(float, u_hi16);
}

// pack 8 f32 -> 8 bf16 via the proven scalar path
__device__ __forceinline__ short8v pack8(const float4 a, const float4 b) {
    short8v r;
    r[0] = (short)f2bf(a.x); r[1] = (short)f2bf(a.y);
    r[2] = (short)f2bf(a.z); r[3] = (short)f2bf(a.w);
    r[4] = (short)f2bf(b.x); r[5] = (short)f2bf(b.y);
    r[6] = (short)f2bf(b.z); r[7] = (short)f2bf(b.w);
    return r;
}

// DPP 16-lane all-lanes sum (VALU only, no DS)
template <int CTRL>
__device__ __forceinline__ float dpp_addf(float x) {
    const int s = __builtin_bit_cast(int, x);
    const int p = __builtin_amdgcn_update_dpp(s, s, CTRL, 0xF, 0xF, true);
    return x + __builtin_bit_cast(float, p);
}
__device__ __forceinline__ float red16(float x) {
    x = dpp_addf<0xB1>(x);
    x = dpp_addf<0x4E>(x);
    x = dpp_addf<0x141>(x);
    x = dpp_addf<0x140>(x);
    return x;
}

// ---------------------------------------------------------------------------
// K0: weight prep (round-7 proven version).
// ---------------------------------------------------------------------------
__global__ __launch_bounds__(256) void k0_prep(
    const float* __restrict__ Wk, const float* __restrict__ Wv,
    const float* __restrict__ Wo, const float* __restrict__ W1,
    const float* __restrict__ W2,
    unsigned short* __restrict__ WkvTf, unsigned short* __restrict__ WoT,
    unsigned short* __restrict__ W1T, unsigned short* __restrict__ W2T)
{
    const int idx = blockIdx.x * 256 + threadIdx.x;   // 163840 total
    if (idx < 16384) {
        const int frag = idx >> 9;          // cc*2 + s
        const int e    = idx & 511;
        const int lane = e >> 3, j = e & 7;
        const int cc = frag >> 1, s = frag & 1;
        const int c  = cc * 16 + (lane & 15);
        const int m  = s * 32 + (lane >> 4) * 8 + j;
        WkvTf[idx] = f2bf((c < 128) ? Wk[(size_t)(128 + m) * 128 + c]
                                    : Wv[(size_t)(128 + m) * 128 + (c - 128)]);
    } else if (idx < 32768) {
        const int j = idx - 16384, c = j >> 7, d = j & 127;
        WoT[j] = f2bf(Wo[(size_t)d * 128 + c]);
    } else if (idx < 98304) {
        const int j = idx - 32768, f = j >> 7, d = j & 127;
        W1T[j] = f2bf(W1[(size_t)d * 512 + f]);
    } else {
        const int j = idx - 98304, c = j >> 9, f = j & 511;
        W2T[j] = f2bf(W2[(size_t)f * 128 + c]);
    }
}

// ---------------------------------------------------------------------------
// K1 (round-15 proven): scalar f32, LDS reads vectorized to ds_read_b128.
// ---------------------------------------------------------------------------
__global__ __launch_bounds__(256) void k1_ln_q_p(
    const float* __restrict__ node_rep, const float* __restrict__ mask,
    const float* __restrict__ ln1_s, const float* __restrict__ ln1_b,
    const float* __restrict__ Wq, const float* __restrict__ bq,
    const float* __restrict__ Wk, const float* __restrict__ bk,
    const float* __restrict__ Wv, const float* __restrict__ bv,
    float* __restrict__ xout, float* __restrict__ qout,
    unsigned short* __restrict__ Pp)
{
    __shared__ float xs[8][DIM];
    const int t = threadIdx.x;
    const int nb = blockIdx.x * 8;
    const int g = t >> 5;
    const int lane = t & 31;
    const int node = nb + g;

    float4 v = reinterpret_cast<const float4*>(node_rep + (size_t)node * DIM)[lane];
    float s1 = v.x + v.y + v.z + v.w;
    float s2 = v.x * v.x + v.y * v.y + v.z * v.z + v.w * v.w;
    #pragma unroll
    for (int off = 16; off; off >>= 1) {
        s1 += __shfl_xor(s1, off, 32);
        s2 += __shfl_xor(s2, off, 32);
    }
    const float mean = s1 * (1.0f / DIM);
    const float var  = s2 * (1.0f / DIM) - mean * mean;
    const float rs   = rsqrtf(var + LN_EPS);
    const float mk   = mask[node];

    float4 sc = reinterpret_cast<const float4*>(ln1_s)[lane];
    float4 of = reinterpret_cast<const float4*>(ln1_b)[lane];
    float4 xo;
    xo.x = ((v.x - mean) * rs * sc.x + of.x) * mk;
    xo.y = ((v.y - mean) * rs * sc.y + of.y) * mk;
    xo.z = ((v.z - mean) * rs * sc.z + of.z) * mk;
    xo.w = ((v.w - mean) * rs * sc.w + of.w) * mk;
    reinterpret_cast<float4*>(xout + (size_t)node * DIM)[lane] = xo;
    const int c0 = lane * 4;
    xs[g][c0 + 0] = xo.x; xs[g][c0 + 1] = xo.y;
    xs[g][c0 + 2] = xo.z; xs[g][c0 + 3] = xo.w;
    __syncthreads();

    const int col = t & 127;
    const int n0  = t >> 7;              // wave-uniform (waves 0,1 -> 0; 2,3 -> 1)
    const int c = t;
    const float* wq = Wq + col;
    const float* wp = (c < 128) ? (Wk + c) : (Wv + (c - 128));

    float accq[4] = {0.f, 0.f, 0.f, 0.f};
    float accp[8] = {0.f, 0.f, 0.f, 0.f, 0.f, 0.f, 0.f, 0.f};
    for (int d = 0; d < DIM; d += 4) {
        const float w0 = wq[(size_t)(d + 0) * 128];
        const float w1 = wq[(size_t)(d + 1) * 128];
        const float w2 = wq[(size_t)(d + 2) * 128];
        const float w3 = wq[(size_t)(d + 3) * 128];
        const float p0 = wp[(size_t)(d + 0) * 128];
        const float p1 = wp[(size_t)(d + 1) * 128];
        const float p2 = wp[(size_t)(d + 2) * 128];
        const float p3 = wp[(size_t)(d + 3) * 128];
        float4 xv[8];
        #pragma unroll
        for (int i = 0; i < 8; ++i)
            xv[i] = *reinterpret_cast<const float4*>(&xs[i][d]);
        #pragma unroll
        for (int i = 0; i < 8; ++i) {
            accp[i] += xv[i].x * p0;
            accp[i] += xv[i].y * p1;
            accp[i] += xv[i].z * p2;
            accp[i] += xv[i].w * p3;
        }
        if (n0 == 0) {
            #pragma unroll
            for (int i = 0; i < 4; ++i) {
                accq[i] += xv[2 * i].x * w0;
                accq[i] += xv[2 * i].y * w1;
                accq[i] += xv[2 * i].z * w2;
                accq[i] += xv[2 * i].w * w3;
            }
        } else {
            #pragma unroll
            for (int i = 0; i < 4; ++i) {
                accq[i] += xv[2 * i + 1].x * w0;
                accq[i] += xv[2 * i + 1].y * w1;
                accq[i] += xv[2 * i + 1].z * w2;
                accq[i] += xv[2 * i + 1].w * w3;
            }
        }
    }
    const float bqv = bq[col];
    #pragma unroll
    for (int i = 0; i < 4; ++i)
        qout[(size_t)(nb + n0 + 2 * i) * DIM + col] = accq[i] + bqv;

    const float bpv = (c < 128) ? bk[c] : bv[c - 128];
    #pragma unroll
    for (int i = 0; i < 8; ++i)
        Pp[(size_t)(nb + i) * 256 + c] = f2bf(accp[i] + bpv);
}

// ---------------------------------------------------------------------------
// K2: phase-split attention, WkvTf staged in LDS (round-17 proven) +
//   SINGLE EDGE READ: afr kept live across both phases (saves 164 MB HBM +
//   ~130 pack-VALU ops per wave). (256,3) -> 170-reg budget, no spills.
// ---------------------------------------------------------------------------
__global__ __launch_bounds__(256, 3) void k2_attn(
    const float* __restrict__ qg, const float* __restrict__ edge_feat,
    const unsigned short* __restrict__ Pp,
    const unsigned short* __restrict__ WkvTf,
    const int* __restrict__ senders,
    float* __restrict__ og)
{
    __shared__ unsigned short wls[32 * 512];   // 32 KB, full WkvTf
    __shared__ unsigned attls[4][8][4][4];     // [wave][head][lg][j], 2 KB

    const int t = threadIdx.x;
    const int w = t >> 6, l = t & 63;
    const int n = blockIdx.x * 4 + w;
    const int l15 = l & 15, lg = l >> 4;

    // stage WkvTf -> LDS: 2048 uint4, 8 per thread, coalesced
    {
        const uint4* src = reinterpret_cast<const uint4*>(WkvTf);
        uint4* dst = reinterpret_cast<uint4*>(wls);
        #pragma unroll
        for (int i = 0; i < 8; ++i)
            dst[i * 256 + t] = src[i * 256 + t];
    }

    const int s0 = senders[n * KNBR + l15];
    const int s1 = senders[n * KNBR + 16 + l15];

    short8v ib1, ib2;
    #pragma unroll
    for (int j = 0; j < 8; ++j) {
        const int m = lg * 8 + j;
        ib1[j] = (m == l15)      ? (short)0x3F80 : (short)0;
        ib2[j] = (m == l15 + 16) ? (short)0x3F80 : (short)0;
    }

    // edge A-fragments: loaded and packed ONCE, live across both phases
    short8v afr[2][2];
    #pragma unroll
    for (int r = 0; r < 2; ++r) {
        #pragma unroll
        for (int s = 0; s < 2; ++s) {
            const float* ep = edge_feat
                + ((size_t)n * KNBR + 16 * r + l15) * EDIM + s * 32 + lg * 8;
            const float4 e0 = *reinterpret_cast<const float4*>(ep);
            const float4 e1 = *reinterpret_cast<const float4*>(ep + 4);
            afr[r][s] = pack8(e0, e1);
        }
    }

    __syncthreads();   // wls ready

    // ---- phase A: kk (cols 0..127) ----
    f32x4 acc[2][8];
    #pragma unroll
    for (int r = 0; r < 2; ++r)
        #pragma unroll
        for (int cc = 0; cc < 8; ++cc)
            acc[r][cc] = (f32x4){0.f, 0.f, 0.f, 0.f};

    #pragma unroll
    for (int cc = 0; cc < 8; ++cc) {
        #pragma unroll
        for (int s = 0; s < 2; ++s) {
            const short8v b = *reinterpret_cast<const short8v*>(
                wls + ((cc * 2 + s) << 9) + l * 8);
            acc[0][cc] = __builtin_amdgcn_mfma_f32_16x16x32_bf16(
                afr[0][s], b, acc[0][cc], 0, 0, 0);
            acc[1][cc] = __builtin_amdgcn_mfma_f32_16x16x32_bf16(
                afr[1][s], b, acc[1][cc], 0, 0, 0);
        }
    }
    #pragma unroll
    for (int c2 = 0; c2 < 4; ++c2) {
        const short8v pa0 = *reinterpret_cast<const short8v*>(
            Pp + (size_t)s0 * 256 + c2 * 32 + lg * 8);
        const short8v pa1 = *reinterpret_cast<const short8v*>(
            Pp + (size_t)s1 * 256 + c2 * 32 + lg * 8);
        acc[0][2 * c2]     = __builtin_amdgcn_mfma_f32_16x16x32_bf16(
            pa0, ib1, acc[0][2 * c2], 0, 0, 0);
        acc[0][2 * c2 + 1] = __builtin_amdgcn_mfma_f32_16x16x32_bf16(
            pa0, ib2, acc[0][2 * c2 + 1], 0, 0, 0);
        acc[1][2 * c2]     = __builtin_amdgcn_mfma_f32_16x16x32_bf16(
            pa1, ib1, acc[1][2 * c2], 0, 0, 0);
        acc[1][2 * c2 + 1] = __builtin_amdgcn_mfma_f32_16x16x32_bf16(
            pa1, ib2, acc[1][2 * c2 + 1], 0, 0, 0);
    }

    // logits -> softmax -> attn weights (x 1/s) -> bf16 packed -> LDS
    #pragma unroll
    for (int h = 0; h < 8; ++h) {
        const float qv = qg[(size_t)n * DIM + h * 16 + l15];
        float tm[8];
        #pragma unroll
        for (int r = 0; r < 2; ++r)
            #pragma unroll
            for (int i = 0; i < 4; ++i)
                tm[r * 4 + i] = acc[r][h][i] * qv;
        #pragma unroll
        for (int k = 0; k < 8; ++k) tm[k] = red16(tm[k]);
        float m = tm[0];
        #pragma unroll
        for (int k = 1; k < 8; ++k) m = fmaxf(m, tm[k]);
        m = fmaxf(m, __shfl_xor(m, 16, 64));
        m = fmaxf(m, __shfl_xor(m, 32, 64));
        float s = 0.f;
        #pragma unroll
        for (int k = 0; k < 8; ++k) {
            tm[k] = __expf((tm[k] - m) * 0.25f);
            s += tm[k];
        }
        s += __shfl_xor(s, 16, 64);
        s += __shfl_xor(s, 32, 64);
        const float inv = 1.0f / s;
        uint4 ap;
        ap.x = (unsigned)f2bf(tm[0] * inv) | ((unsigned)f2bf(tm[1] * inv) << 16);
        ap.y = (unsigned)f2bf(tm[2] * inv) | ((unsigned)f2bf(tm[3] * inv) << 16);
        ap.z = (unsigned)f2bf(tm[4] * inv) | ((unsigned)f2bf(tm[5] * inv) << 16);
        ap.w = (unsigned)f2bf(tm[6] * inv) | ((unsigned)f2bf(tm[7] * inv) << 16);
        if (l15 == 0)
            *reinterpret_cast<uint4*>(&attls[w][h][lg][0]) = ap;
    }

    // ---- phase B: vv (cols 128..255), acc registers reused, afr still live --
    #pragma unroll
    for (int r = 0; r < 2; ++r)
        #pragma unroll
        for (int cc = 0; cc < 8; ++cc)
            acc[r][cc] = (f32x4){0.f, 0.f, 0.f, 0.f};

    #pragma unroll
    for (int cc = 0; cc < 8; ++cc) {
        #pragma unroll
        for (int s = 0; s < 2; ++s) {
            const short8v b = *reinterpret_cast<const short8v*>(
                wls + (((8 + cc) * 2 + s) << 9) + l * 8);
            acc[0][cc] = __builtin_amdgcn_mfma_f32_16x16x32_bf16(
                afr[0][s], b, acc[0][cc], 0, 0, 0);
            acc[1][cc] = __builtin_amdgcn_mfma_f32_16x16x32_bf16(
                afr[1][s], b, acc[1][cc], 0, 0, 0);
        }
    }
    #pragma unroll
    for (int c2 = 0; c2 < 4; ++c2) {
        const short8v pa0 = *reinterpret_cast<const short8v*>(
            Pp + (size_t)s0 * 256 + 128 + c2 * 32 + lg * 8);
        const short8v pa1 = *reinterpret_cast<const short8v*>(
            Pp + (size_t)s1 * 256 + 128 + c2 * 32 + lg * 8);
        acc[0][2 * c2]     = __builtin_amdgcn_mfma_f32_16x16x32_bf16(
            pa0, ib1, acc[0][2 * c2], 0, 0, 0);
        acc[0][2 * c2 + 1] = __builtin_amdgcn_mfma_f32_16x16x32_bf16(
            pa0, ib2, acc[0][2 * c2 + 1], 0, 0, 0);
        acc[1][2 * c2]     = __builtin_amdgcn_mfma_f32_16x16x32_bf16(
            pa1, ib1, acc[1][2 * c2], 0, 0, 0);
        acc[1][2 * c2 + 1] = __builtin_amdgcn_mfma_f32_16x16x32_bf16(
            pa1, ib2, acc[1][2 * c2 + 1], 0, 0, 0);
    }

    // PV per head: attn weights (incl. 1/s) read back from LDS (broadcast)
    #pragma unroll
    for (int h = 0; h < 8; ++h) {
        const uint4 ap = *reinterpret_cast<const uint4*>(&attls[w][h][lg][0]);
        float ov = 0.f;
        ov += bfhi2f(ap.x << 16)         * acc[0][h][0];
        ov += bfhi2f(ap.x & 0xffff0000u) * acc[0][h][1];
        ov += bfhi2f(ap.y << 16)         * acc[0][h][2];
        ov += bfhi2f(ap.y & 0xffff0000u) * acc[0][h][3];
        ov += bfhi2f(ap.z << 16)         * acc[1][h][0];
        ov += bfhi2f(ap.z & 0xffff0000u) * acc[1][h][1];
        ov += bfhi2f(ap.w << 16)         * acc[1][h][2];
        ov += bfhi2f(ap.w & 0xffff0000u) * acc[1][h][3];
        ov += __shfl_xor(ov, 16, 64);
        ov += __shfl_xor(ov, 32, 64);
        if (lg == 0)
            og[(size_t)n * DIM + h * 16 + l15] = ov;
    }
}

// ---------------------------------------------------------------------------
// K3 (round-16 proven): 1 wave per block (16 nodes), no barriers.
// ---------------------------------------------------------------------------
__device__ __forceinline__ void lds_wr16(unsigned short* base, int row, int col,
                                         unsigned short v) {
    const int byte = row * 256 + (((col * 2) ^ ((row & 7) << 4)));
    *reinterpret_cast<unsigned short*>(reinterpret_cast<char*>(base) + byte) = v;
}
__device__ __forceinline__ short8v lds_rd128(const unsigned short* base, int row,
                                             int colbyte) {
    const int byte = row * 256 + ((colbyte) ^ ((row & 7) << 4));
    return *reinterpret_cast<const short8v*>(
        reinterpret_cast<const char*>(base) + byte);
}

__global__ __launch_bounds__(64) void k3_ffn(
    const float* __restrict__ og, const float* __restrict__ xg,
    const float* __restrict__ mask,
    const unsigned short* __restrict__ WoT, const float* __restrict__ bo,
    const float* __restrict__ ln2_s, const float* __restrict__ ln2_b,
    const unsigned short* __restrict__ W1T, const float* __restrict__ b1,
    const unsigned short* __restrict__ W2T, const float* __restrict__ b2,
    float* __restrict__ outp)
{
    __shared__ unsigned short hls[16 * 128];
    __shared__ unsigned short tls[16 * 128];

    const int l = threadIdx.x;          // 0..63, one wave
    const int l15 = l & 15, lg = l >> 4;
    const int nb = blockIdx.x * 16;
    const int arow = l15;
    const int anode = nb + arow;
    const int r0 = lg * 4;

    float mk[4];
    #pragma unroll
    for (int i = 0; i < 4; ++i) {
        const int node = nb + r0 + i;
        mk[i] = (node < N_NODES) ? mask[node] : 0.f;
    }

    f32x4 acc1[8];
    #pragma unroll
    for (int ct = 0; ct < 8; ++ct) acc1[ct] = (f32x4){0.f, 0.f, 0.f, 0.f};
    #pragma unroll
    for (int kc = 0; kc < 4; ++kc) {
        short8v afr = {0, 0, 0, 0, 0, 0, 0, 0};
        if (anode < N_NODES) {
            const float* op = og + (size_t)anode * DIM + kc * 32 + lg * 8;
            const float4 e0 = *reinterpret_cast<const float4*>(op);
            const float4 e1 = *reinterpret_cast<const float4*>(op + 4);
            afr = pack8(e0, e1);
        }
        #pragma unroll
        for (int ct = 0; ct < 8; ++ct) {
            const short8v b = *reinterpret_cast<const short8v*>(
                WoT + (size_t)(ct * 16 + l15) * DIM + kc * 32 + lg * 8);
            acc1[ct] = __builtin_amdgcn_mfma_f32_16x16x32_bf16(afr, b, acc1[ct], 0, 0, 0);
        }
    }

    float s1[4] = {0.f, 0.f, 0.f, 0.f}, s2[4] = {0.f, 0.f, 0.f, 0.f};
    #pragma unroll
    for (int ct = 0; ct < 8; ++ct) {
        const float bov = bo[ct * 16 + l15];
        #pragma unroll
        for (int i = 0; i < 4; ++i) {
            const float v2 = (acc1[ct][i] + bov) * mk[i];
            acc1[ct][i] = v2;
            s1[i] += v2; s2[i] += v2 * v2;
        }
    }
    #pragma unroll
    for (int off = 1; off <= 8; off <<= 1) {
        #pragma unroll
        for (int i = 0; i < 4; ++i) {
            s1[i] += __shfl_xor(s1[i], off, 64);
            s2[i] += __shfl_xor(s2[i], off, 64);
        }
    }
    float mean[4], rsv[4];
    #pragma unroll
    for (int i = 0; i < 4; ++i) {
        mean[i] = s1[i] * (1.0f / OUTD);
        const float var = s2[i] * (1.0f / OUTD) - mean[i] * mean[i];
        rsv[i] = rsqrtf(var + LN_EPS);
    }
    #pragma unroll
    for (int ct = 0; ct < 8; ++ct) {
        const int col = ct * 16 + l15;
        const float sc = ln2_s[col], ofs = ln2_b[col];
        #pragma unroll
        for (int i = 0; i < 4; ++i) {
            const float h = (acc1[ct][i] - mean[i]) * rsv[i] * sc + ofs;
            lds_wr16(hls, r0 + i, col, f2bf(h));
        }
    }

    short8v hfr[4];
    #pragma unroll
    for (int kc = 0; kc < 4; ++kc)
        hfr[kc] = lds_rd128(hls, arow, kc * 64 + lg * 16);

    f32x4 acc3[8];
    #pragma unroll
    for (int ct = 0; ct < 8; ++ct) acc3[ct] = (f32x4){0.f, 0.f, 0.f, 0.f};

    for (int chunk = 0; chunk < 4; ++chunk) {
        f32x4 acc2[8];
        #pragma unroll
        for (int ct = 0; ct < 8; ++ct) acc2[ct] = (f32x4){0.f, 0.f, 0.f, 0.f};
        #pragma unroll
        for (int kc = 0; kc < 4; ++kc) {
            #pragma unroll
            for (int ct = 0; ct < 8; ++ct) {
                const short8v b = *reinterpret_cast<const short8v*>(
                    W1T + (size_t)(chunk * 128 + ct * 16 + l15) * DIM + kc * 32 + lg * 8);
                acc2[ct] = __builtin_amdgcn_mfma_f32_16x16x32_bf16(hfr[kc], b, acc2[ct], 0, 0, 0);
            }
        }
        #pragma unroll
        for (int ct = 0; ct < 8; ++ct) {
            const float bv = b1[chunk * 128 + ct * 16 + l15];
            #pragma unroll
            for (int i = 0; i < 4; ++i) {
                const float tv = fmaxf(acc2[ct][i] + bv, 0.f);
                lds_wr16(tls, r0 + i, ct * 16 + l15, f2bf(tv));
            }
        }
        #pragma unroll
        for (int kc = 0; kc < 4; ++kc) {
            const short8v tfr = lds_rd128(tls, arow, kc * 64 + lg * 16);
            #pragma unroll
            for (int ct = 0; ct < 8; ++ct) {
                const short8v b = *reinterpret_cast<const short8v*>(
                    W2T + (size_t)(ct * 16 + l15) * FFD + chunk * 128 + kc * 32 + lg * 8);
                acc3[ct] = __builtin_amdgcn_mfma_f32_16x16x32_bf16(tfr, b, acc3[ct], 0, 0, 0);
            }
        }
    }

    #pragma unroll
    for (int ct = 0; ct < 8; ++ct) {
        const int col = ct * 16 + l15;
        const float b2v = b2[col];
        #pragma unroll
        for (int i = 0; i < 4; ++i) {
            const int node = nb + r0 + i;
            if (node < N_NODES) {
                const float f = (acc3[ct][i] + b2v) * mk[i];
                outp[(size_t)node * DIM + col] = xg[(size_t)node * DIM + col] + f;
            }
        }
    }
}

// ---------------------------------------------------------------------------
extern "C" void kernel_launch(void* const* d_in, const int* in_sizes, int n_in,
                              void* d_out, int out_size, void* d_ws, size_t ws_size,
                              hipStream_t stream)
{
    const float* node_rep = (const float*)d_in[0];
    const float* mask     = (const float*)d_in[1];
    const float* edge_feat= (const float*)d_in[2];
    const float* Wq = (const float*)d_in[3];
    const float* bq = (const float*)d_in[4];
    const float* Wk = (const float*)d_in[5];
    const float* bk = (const float*)d_in[6];
    const float* Wv = (const float*)d_in[7];
    const float* bv = (const float*)d_in[8];
    const float* Wo = (const float*)d_in[9];
    const float* bo = (const float*)d_in[10];
    const float* ln1_s = (const float*)d_in[11];
    const float* ln1_b = (const float*)d_in[12];
    const float* ln2_s = (const float*)d_in[13];
    const float* ln2_b = (const float*)d_in[14];
    const float* W1 = (const float*)d_in[15];
    const float* b1 = (const float*)d_in[16];
    const float* W2 = (const float*)d_in[17];
    const float* b2 = (const float*)d_in[18];
    const int* senders = (const int*)d_in[19];

    float* out = (float*)d_out;
    float* xg = (float*)d_ws;                           // [N,128] f32
    float* qg = xg + (size_t)N_NODES * DIM;             // [N,128] f32
    float* og = qg + (size_t)N_NODES * DIM;             // [N,128] f32
    unsigned short* Pp    = (unsigned short*)(og + (size_t)N_NODES * DIM);  // [N,256] bf16
    unsigned short* WkvTf = Pp + (size_t)N_NODES * 256;  // [32 frag][512]
    unsigned short* WoT   = WkvTf + 256 * 64;            // [128,128]
    unsigned short* W1T   = WoT + 128 * 128;             // [512,128]
    unsigned short* W2T   = W1T + 512 * 128;             // [128,512]

    hipLaunchKernelGGL(k0_prep, dim3(640), dim3(256), 0, stream,
                       Wk, Wv, Wo, W1, W2, WkvTf, WoT, W1T, W2T);
    hipLaunchKernelGGL(k1_ln_q_p, dim3(N_NODES / 8), dim3(256), 0, stream,
                       node_rep, mask, ln1_s, ln1_b, Wq, bq, Wk, bk, Wv, bv,
                       xg, qg, Pp);
    hipLaunchKernelGGL(k2_attn, dim3(N_NODES / 4), dim3(256), 0, stream,
                       qg, edge_feat, Pp, WkvTf, senders, og);
    hipLaunchKernelGGL(k3_ffn, dim3((N_NODES + 15) / 16), dim3(64), 0, stream,
                       og, xg, mask, WoT, bo, ln2_s, ln2_b, W1T, b1, W2T, b2, out);
}